// Round 4
// baseline (815.690 us; speedup 1.0000x reference)
//
#include <hip/hip_runtime.h>
#include <cstdint>

#define HIDDEN 128

typedef unsigned short u16;
using frag_t   = __attribute__((ext_vector_type(8))) short;   // 8 bf16 (4 VGPRs)
using f32x4_t  = __attribute__((ext_vector_type(4))) float;   // MFMA accumulator
using ushort8_t = __attribute__((ext_vector_type(8))) unsigned short;

__device__ __forceinline__ float bf2f(u16 u) {
    union { unsigned int i; float f; } c;
    c.i = ((unsigned int)u) << 16;
    return c.f;
}
__device__ __forceinline__ u16 f2bf(float f) {
    unsigned int u = __float_as_uint(f);
    unsigned int r = (u + 0x7fffu + ((u >> 16) & 1u)) >> 16;   // RNE
    return (u16)r;
}

// ---------------- software grid barrier (all blocks co-resident by capacity) ----------------
// monotonic counter, increasing targets; cnt zeroed by host memset each launch.
__device__ __forceinline__ void gbar(int* cnt, int target) {
    __syncthreads();
    if (threadIdx.x == 0) {
        __threadfence();   // device-scope: prior writes visible before arrival
        __hip_atomic_fetch_add(cnt, 1, __ATOMIC_RELEASE, __HIP_MEMORY_SCOPE_AGENT);
        while (__hip_atomic_load(cnt, __ATOMIC_ACQUIRE, __HIP_MEMORY_SCOPE_AGENT) < target)
            __builtin_amdgcn_s_sleep(2);
    }
    __syncthreads();
}

// ---------------- CSR build + prep fused (edge_index arrives as int32 from harness) ----------------
// XCD-range partitioning: blocks with blockIdx&7==r own dst range [r*npr, (r+1)*npr).

__global__ void k_hist_prep(const int* __restrict__ ei, int E, int* __restrict__ deg, int npr,
                            const float* __restrict__ x,
                            const float* __restrict__ W_in,
                            const float* __restrict__ W_self,
                            const float* __restrict__ W_nbr,
                            u16* __restrict__ xf,
                            u16* __restrict__ WtI_hi, u16* __restrict__ WtI_lo,
                            u16* __restrict__ WtS_hi, u16* __restrict__ WtS_lo,
                            u16* __restrict__ WtN_hi, u16* __restrict__ WtN_lo,
                            int L, int nxg) {
    // ---- histogram part ----
    {
        int r  = blockIdx.x & 7;
        int lo = r * npr, hi = lo + npr;
        int nb = gridDim.x >> 3;
        int bi = blockIdx.x >> 3;
        int tid = bi * blockDim.x + threadIdx.x;
        int stride = nb * blockDim.x;
        if ((E & 3) == 0) {
            const int4* d4 = (const int4*)(ei + E);
            int nch = E >> 2;
            for (int c = tid; c < nch; c += stride) {
                int4 d = d4[c];
                if (d.x >= lo && d.x < hi) atomicAdd(&deg[d.x], 1);
                if (d.y >= lo && d.y < hi) atomicAdd(&deg[d.y], 1);
                if (d.z >= lo && d.z < hi) atomicAdd(&deg[d.z], 1);
                if (d.w >= lo && d.w < hi) atomicAdd(&deg[d.w], 1);
            }
        } else {
            for (int e = tid; e < E; e += stride) {
                int d = ei[E + e];
                if (d >= lo && d < hi) atomicAdd(&deg[d], 1);
            }
        }
    }
    // ---- prep part ----
    {
        int nIn = 64 * 128;
        int nSq = L * 128 * 128;
        int wtot = nIn + 2 * nSq;
        int total = wtot + nxg;
        int stride = gridDim.x * blockDim.x;
        for (int i = blockIdx.x * blockDim.x + threadIdx.x; i < total; i += stride) {
            if (i >= wtot) {
                int t = i - wtot;
                int row = t >> 3, c = t & 7;
                const float4* xs = (const float4*)(x + (size_t)row * 64 + c * 8);
                float4 v0 = xs[0], v1 = xs[1];
                ushort8_t o;
                o[0] = f2bf(v0.x); o[1] = f2bf(v0.y); o[2] = f2bf(v0.z); o[3] = f2bf(v0.w);
                o[4] = f2bf(v1.x); o[5] = f2bf(v1.y); o[6] = f2bf(v1.z); o[7] = f2bf(v1.w);
                int T = row >> 4, m = row & 15;
                int f = c >> 2, q = c & 3;
                *(ushort8_t*)&xf[((size_t)(T * 2 + f) * 64 + q * 16 + m) * 8] = o;
            } else {
                float v; u16* phi; u16* plo; int o;
                if (i < nIn) {
                    int n = i / 64, k = i % 64;
                    v = W_in[k * 128 + n]; phi = WtI_hi; plo = WtI_lo; o = n * 64 + k;
                } else if (i < nIn + nSq) {
                    int t = i - nIn;
                    int l = t / (128 * 128), r = t % (128 * 128);
                    int n = r / 128, k = r % 128;
                    v = W_self[l * 128 * 128 + k * 128 + n]; phi = WtS_hi; plo = WtS_lo;
                    o = l * 128 * 128 + n * 128 + k;
                } else {
                    int t = i - nIn - nSq;
                    int l = t / (128 * 128), r = t % (128 * 128);
                    int n = r / 128, k = r % 128;
                    v = W_nbr[l * 128 * 128 + k * 128 + n]; phi = WtN_hi; plo = WtN_lo;
                    o = l * 128 * 128 + n * 128 + k;
                }
                u16 hi = f2bf(v);
                phi[o] = hi;
                plo[o] = f2bf(v - bf2f(hi));
            }
        }
    }
}

__global__ void k_scan1(const int* __restrict__ deg, int* __restrict__ rowp,
                        int* __restrict__ bsums, int n) {
    __shared__ int sh[1024];
    int t = threadIdx.x;
    int base = blockIdx.x * 1024;
    int v = (base + t < n) ? deg[base + t] : 0;
    sh[t] = v;
    __syncthreads();
    for (int off = 1; off < 1024; off <<= 1) {
        int x = sh[t];
        int y = (t >= off) ? sh[t - off] : 0;
        __syncthreads();
        sh[t] = x + y;
        __syncthreads();
    }
    if (base + t < n) rowp[base + t + 1] = sh[t];
    if (t == 1023) bsums[blockIdx.x] = sh[1023];
}

// merged scan2+scan3: each block locally re-scans bsums in LDS, applies offset, writes fillp.
__global__ void k_scan_tail(int* __restrict__ rowp, const int* __restrict__ bsums,
                            int* __restrict__ fillp, int n, int nb) {
    __shared__ int sh[1024];
    int t = threadIdx.x;
    int b = blockIdx.x;
    sh[t] = (t < nb) ? bsums[t] : 0;
    __syncthreads();
    for (int off = 1; off < 1024; off <<= 1) {
        int x = sh[t];
        int y = (t >= off) ? sh[t - off] : 0;
        __syncthreads();
        sh[t] = x + y;
        __syncthreads();
    }
    int boff = (b == 0) ? 0 : sh[b - 1];
    int base = b * 1024;
    if (base + t < n) {
        int v = rowp[base + t + 1] + boff;
        rowp[base + t + 1] = v;
        if (base + t + 1 < n) fillp[base + t + 1] = v;
    }
    if (b == 0 && t == 0) { rowp[0] = 0; fillp[0] = 0; }
}

__global__ void k_fill(const int* __restrict__ ei, int E,
                       int* __restrict__ fillpos, int* __restrict__ colx, int npr) {
    int r  = blockIdx.x & 7;
    int lo = r * npr, hi = lo + npr;
    int nb = gridDim.x >> 3;
    int bi = blockIdx.x >> 3;
    int tid = bi * blockDim.x + threadIdx.x;
    int stride = nb * blockDim.x;
    if ((E & 3) == 0) {
        const int4* s4 = (const int4*)ei;
        const int4* d4 = (const int4*)(ei + E);
        int nch = E >> 2;
        for (int c = tid; c < nch; c += stride) {
            int4 d = d4[c];
            bool m0 = d.x >= lo && d.x < hi;
            bool m1 = d.y >= lo && d.y < hi;
            bool m2 = d.z >= lo && d.z < hi;
            bool m3 = d.w >= lo && d.w < hi;
            if (m0 | m1 | m2 | m3) {
                int4 s = s4[c];
                if (m0) colx[atomicAdd(&fillpos[d.x], 1)] = s.x;
                if (m1) colx[atomicAdd(&fillpos[d.y], 1)] = s.y;
                if (m2) colx[atomicAdd(&fillpos[d.z], 1)] = s.z;
                if (m3) colx[atomicAdd(&fillpos[d.w], 1)] = s.w;
            }
        }
    } else {
        for (int e = tid; e < E; e += stride) {
            int d = ei[E + e];
            if (d >= lo && d < hi) colx[atomicAdd(&fillpos[d], 1)] = ei[e];
        }
    }
}

// ---------------- device phase: aggregation (grid-stride; body identical to old k_agg) ----------------

__device__ __forceinline__ void dev_agg(const ushort8_t* __restrict__ hb8,
                                        const int* __restrict__ rowp,
                                        const int* __restrict__ colx,
                                        u16* __restrict__ Sf, int n) {
    int lane = threadIdx.x & 15;
    int ngr = (gridDim.x * blockDim.x) >> 4;
    for (int g = (blockIdx.x * blockDim.x + threadIdx.x) >> 4; g < n; g += ngr) {
        int beg = rowp[g];
        int end = rowp[g + 1];
        float a0[8], a1[8];
#pragma unroll
        for (int j = 0; j < 8; ++j) { a0[j] = 0.f; a1[j] = 0.f; }
        int e = beg;
        for (; e + 7 < end; e += 8) {
            int s0 = colx[e],     s1 = colx[e + 1], s2 = colx[e + 2], s3 = colx[e + 3];
            int s4 = colx[e + 4], s5 = colx[e + 5], s6 = colx[e + 6], s7 = colx[e + 7];
            ushort8_t v0 = hb8[(size_t)s0 * 16 + lane];
            ushort8_t v1 = hb8[(size_t)s1 * 16 + lane];
            ushort8_t v2 = hb8[(size_t)s2 * 16 + lane];
            ushort8_t v3 = hb8[(size_t)s3 * 16 + lane];
            ushort8_t v4 = hb8[(size_t)s4 * 16 + lane];
            ushort8_t v5 = hb8[(size_t)s5 * 16 + lane];
            ushort8_t v6 = hb8[(size_t)s6 * 16 + lane];
            ushort8_t v7 = hb8[(size_t)s7 * 16 + lane];
#pragma unroll
            for (int j = 0; j < 8; ++j) {
                a0[j] += bf2f(v0[j]); a1[j] += bf2f(v1[j]);
                a0[j] += bf2f(v2[j]); a1[j] += bf2f(v3[j]);
                a0[j] += bf2f(v4[j]); a1[j] += bf2f(v5[j]);
                a0[j] += bf2f(v6[j]); a1[j] += bf2f(v7[j]);
            }
        }
        for (; e + 3 < end; e += 4) {
            int s0 = colx[e], s1 = colx[e + 1], s2 = colx[e + 2], s3 = colx[e + 3];
            ushort8_t v0 = hb8[(size_t)s0 * 16 + lane];
            ushort8_t v1 = hb8[(size_t)s1 * 16 + lane];
            ushort8_t v2 = hb8[(size_t)s2 * 16 + lane];
            ushort8_t v3 = hb8[(size_t)s3 * 16 + lane];
#pragma unroll
            for (int j = 0; j < 8; ++j) {
                a0[j] += bf2f(v0[j]); a1[j] += bf2f(v1[j]);
                a0[j] += bf2f(v2[j]); a1[j] += bf2f(v3[j]);
            }
        }
        for (; e < end; ++e) {
            int s = colx[e];
            ushort8_t v = hb8[(size_t)s * 16 + lane];
#pragma unroll
            for (int j = 0; j < 8; ++j) a0[j] += bf2f(v[j]);
        }
        int deg = end - beg;
        float inv = 1.0f / (float)(deg > 1 ? deg : 1);
        ushort8_t o;
#pragma unroll
        for (int j = 0; j < 8; ++j) o[j] = f2bf((a0[j] + a1[j]) * inv);
        int T = g >> 4, m = g & 15;
        *(ushort8_t*)&Sf[((size_t)(T * 4 + (lane >> 2)) * 64 + (lane & 3) * 16 + m) * 8] = o;
    }
}

// ---------------- device phase: MFMA GEMM (body identical to old k_gemm_mfma) ----------------
// step = gridDim/2; ng=(b>>3)&1 pairs col-halves on the same XCD for A-row L2 reuse.

template <int KF1, int KF2, int DO_ELU>
__device__ __forceinline__ void dev_gemm(
    const u16* __restrict__ A1f, const u16* __restrict__ A2f,
    const u16* __restrict__ B1h, const u16* __restrict__ B1l,
    const u16* __restrict__ B2h, const u16* __restrict__ B2l,
    const float* __restrict__ bias, float* __restrict__ C,
    u16* __restrict__ Hrow, u16* __restrict__ Hf,
    int M)
{
    constexpr int K1 = KF1 * 32;
    constexpr int K2 = KF2 * 32;
    constexpr int KF = KF1 + KF2;
    int lane = threadIdx.x & 63;
    int w    = threadIdx.x >> 6;
    int m16  = lane & 15;
    int quad = lane >> 4;
    int kq   = quad * 8;
    int ng   = (blockIdx.x >> 3) & 1;
    int mtb  = (blockIdx.x & 7) | ((blockIdx.x >> 4) << 3);   // [0, gridDim/2)
    int ncol = (ng * 4 + w) * 16 + m16;

    frag_t bh[KF], bl[KF];
    if constexpr (KF1 > 0) {
#pragma unroll
        for (int f = 0; f < KF1; ++f) {
            bh[f] = *(const frag_t*)&B1h[(size_t)ncol * K1 + f * 32 + kq];
            bl[f] = *(const frag_t*)&B1l[(size_t)ncol * K1 + f * 32 + kq];
        }
    }
    if constexpr (KF2 > 0) {
#pragma unroll
        for (int f = 0; f < KF2; ++f) {
            bh[KF1 + f] = *(const frag_t*)&B2h[(size_t)ncol * K2 + f * 32 + kq];
            bl[KF1 + f] = *(const frag_t*)&B2l[(size_t)ncol * K2 + f * 32 + kq];
        }
    }

    float bv = bias[ncol];
    int nMT  = (M + 31) >> 5;
    int step = gridDim.x >> 1;
    int fcol = ncol >> 5;
    int qcol = (ncol & 31) >> 3;
    int jcol = ncol & 7;

    auto loadA = [&](int mt, frag_t (&a0)[KF], frag_t (&a1)[KF]) {
        int T0 = mt * 2, T1 = T0 + 1;   // padded alloc: no guards
        if constexpr (KF1 > 0) {
#pragma unroll
            for (int f = 0; f < KF1; ++f) {
                a0[f] = *(const frag_t*)&A1f[((size_t)(T0 * KF1 + f) * 64 + lane) * 8];
                a1[f] = *(const frag_t*)&A1f[((size_t)(T1 * KF1 + f) * 64 + lane) * 8];
            }
        }
        if constexpr (KF2 > 0) {
#pragma unroll
            for (int f = 0; f < KF2; ++f) {
                a0[KF1 + f] = *(const frag_t*)&A2f[((size_t)(T0 * KF2 + f) * 64 + lane) * 8];
                a1[KF1 + f] = *(const frag_t*)&A2f[((size_t)(T1 * KF2 + f) * 64 + lane) * 8];
            }
        }
    };

    auto compute = [&](int mt, frag_t (&a0)[KF], frag_t (&a1)[KF]) {
        f32x4_t acc0 = (f32x4_t){0.f, 0.f, 0.f, 0.f};
        f32x4_t acc1 = (f32x4_t){0.f, 0.f, 0.f, 0.f};
#pragma unroll
        for (int f = 0; f < KF; ++f) {
            acc0 = __builtin_amdgcn_mfma_f32_16x16x32_bf16(a0[f], bh[f], acc0, 0, 0, 0);
            acc1 = __builtin_amdgcn_mfma_f32_16x16x32_bf16(a1[f], bh[f], acc1, 0, 0, 0);
            acc0 = __builtin_amdgcn_mfma_f32_16x16x32_bf16(a0[f], bl[f], acc0, 0, 0, 0);
            acc1 = __builtin_amdgcn_mfma_f32_16x16x32_bf16(a1[f], bl[f], acc1, 0, 0, 0);
        }
        int rb = mt * 32 + quad * 4;
#pragma unroll
        for (int r = 0; r < 4; ++r) {
#pragma unroll
            for (int half = 0; half < 2; ++half) {
                int row = rb + r + half * 16;
                float av = half ? acc1[r] : acc0[r];
                if (row < M) {
                    float v = av + bv;
                    if constexpr (DO_ELU) v = (v > 0.f) ? v : expm1f(v);
                    if (C) C[(size_t)row * HIDDEN + ncol] = v;
                    if (Hrow) {
                        u16 hv = f2bf(v);
                        Hrow[(size_t)row * HIDDEN + ncol] = hv;
                        Hf[((size_t)((row >> 4) * 4 + fcol) * 64 + qcol * 16 + (row & 15)) * 8 + jcol] = hv;
                    }
                }
            }
        }
    };

    int mt = mtb;
    if (mt < nMT) {     // guarded skip (no return: barriers follow in caller)
        frag_t xa0[KF], xa1[KF], ya0[KF], ya1[KF];
        loadA(mt, xa0, xa1);
        while (true) {
            int mt2 = mt + step;
            if (mt2 < nMT) loadA(mt2, ya0, ya1);       // prefetch under compute(mt)
            compute(mt, xa0, xa1);
            if (mt2 >= nMT) break;
            int mt3 = mt2 + step;
            if (mt3 < nMT) loadA(mt3, xa0, xa1);       // prefetch under compute(mt2)
            compute(mt2, ya0, ya1);
            if (mt3 >= nMT) break;
            mt = mt3;
        }
    }
}

// ---------------- persistent mega-kernel: gemm_in + L x (agg, gemm) with grid barriers ----
// grid = 512 blocks x 256 thr, __launch_bounds__(256,2) => exactly 2 blocks/CU on 256 CUs:
// all blocks co-resident by capacity => software barrier is safe.

__global__ __launch_bounds__(256, 2) void k_mega(
    const u16* __restrict__ xf,
    const u16* __restrict__ WtI_hi, const u16* __restrict__ WtI_lo,
    const u16* __restrict__ WtS_hi, const u16* __restrict__ WtS_lo,
    const u16* __restrict__ WtN_hi, const u16* __restrict__ WtN_lo,
    const float* __restrict__ b_in, const float* __restrict__ b_self,
    const int* __restrict__ rowp, const int* __restrict__ colx,
    u16* __restrict__ hRowA, u16* __restrict__ hfA,
    u16* __restrict__ hRowB, u16* __restrict__ hfB,
    u16* __restrict__ Sf,
    float* __restrict__ out,
    int N, int L, int* __restrict__ cnt)
{
    int nb = gridDim.x;
    int bt = nb;

    // P0: input projection  h = bf16(x @ W_in + b_in)
    dev_gemm<2, 0, 0>(xf, nullptr, WtI_hi, WtI_lo, nullptr, nullptr,
                      b_in, nullptr, hRowA, hfA, N);
    gbar(cnt, bt); bt += nb;

    u16* curRow = hRowA; u16* curF = hfA;
    u16* nxtRow = hRowB; u16* nxtF = hfB;

    for (int l = 0; l < L; ++l) {
        dev_agg((const ushort8_t*)curRow, rowp, colx, Sf, N);
        gbar(cnt, bt); bt += nb;

        const u16* Wsh = WtS_hi + (size_t)l * 128 * 128;
        const u16* Wsl = WtS_lo + (size_t)l * 128 * 128;
        const u16* Wnh = WtN_hi + (size_t)l * 128 * 128;
        const u16* Wnl = WtN_lo + (size_t)l * 128 * 128;
        const float* bs = b_self + (size_t)l * HIDDEN;
        bool last = (l == L - 1);
        dev_gemm<4, 4, 1>(curF, Sf, Wsh, Wsl, Wnh, Wnl, bs,
                          last ? out : nullptr,
                          last ? nullptr : nxtRow, last ? nullptr : nxtF, N);
        if (!last) {
            gbar(cnt, bt); bt += nb;
            u16* tr = curRow; curRow = nxtRow; nxtRow = tr;
            u16* tf = curF;   curF = nxtF;     nxtF = tf;
        }
    }
}

// ---------------- launch ----------------

extern "C" void kernel_launch(void* const* d_in, const int* in_sizes, int n_in,
                              void* d_out, int out_size, void* d_ws, size_t ws_size,
                              hipStream_t stream) {
    const float* x        = (const float*)d_in[0];
    const int* ei         = (const int*)d_in[1];
    const float* W_in     = (const float*)d_in[2];
    const float* b_in     = (const float*)d_in[3];
    const float* W_self   = (const float*)d_in[4];
    const float* b_self   = (const float*)d_in[5];
    const float* W_nbr    = (const float*)d_in[6];
    float* out = (float*)d_out;

    const int IN_FEAT = 64;
    int N = in_sizes[0] / IN_FEAT;           // 50000
    int E = in_sizes[1] / 2;                 // 800000
    int L = in_sizes[4] / (HIDDEN * HIDDEN); // 3

    char* ws = (char*)d_ws;
    size_t off = 0;
    auto alloc = [&](size_t bytes) -> void* {
        void* p = ws + off;
        off = (off + bytes + 255) & ~(size_t)255;
        return p;
    };

    int nT = ((N + 31) / 32) * 2;            // 16-row tiles, padded to macro-tile pairs

    u16* hRowA = (u16*)alloc((size_t)N * HIDDEN * 2);
    u16* hRowB = (u16*)alloc((size_t)N * HIDDEN * 2);
    u16* hfA   = (u16*)alloc((size_t)nT * 4 * 64 * 8 * 2);   // KF=4 frag-major
    u16* hfB   = (u16*)alloc((size_t)nT * 4 * 64 * 8 * 2);
    u16* xf    = (u16*)alloc((size_t)nT * 2 * 64 * 8 * 2);   // KF=2
    u16* Sf    = (u16*)alloc((size_t)nT * 4 * 64 * 8 * 2);
    u16* WtI_hi = (u16*)alloc(128 * 64 * 2);
    u16* WtI_lo = (u16*)alloc(128 * 64 * 2);
    u16* WtS_hi = (u16*)alloc((size_t)L * 128 * 128 * 2);
    u16* WtS_lo = (u16*)alloc((size_t)L * 128 * 128 * 2);
    u16* WtN_hi = (u16*)alloc((size_t)L * 128 * 128 * 2);
    u16* WtN_lo = (u16*)alloc((size_t)L * 128 * 128 * 2);
    int* deg   = (int*)alloc((size_t)(N + 64) * sizeof(int));   // +cnt tail (zeroed together)
    int* cnt   = deg + N;
    int* rowp  = (int*)alloc((size_t)(N + 1) * sizeof(int));
    int* fillp = (int*)alloc((size_t)N * sizeof(int));
    int* colx  = (int*)alloc((size_t)E * sizeof(int));
    int* bsums = (int*)alloc(1024 * sizeof(int));

    int npr = (N + 7) / 8;   // nodes per XCD range

    // CSR build (XCD-range-partitioned scatters) with prep fused into hist; zeroes cnt too
    hipMemsetAsync(deg, 0, (size_t)(N + 64) * sizeof(int), stream);
    k_hist_prep<<<2048, 256, 0, stream>>>(ei, E, deg, npr,
                                          x, W_in, W_self, W_nbr, xf,
                                          WtI_hi, WtI_lo, WtS_hi, WtS_lo,
                                          WtN_hi, WtN_lo, L, N * 8);
    int nb = (N + 1023) / 1024;
    k_scan1<<<nb, 1024, 0, stream>>>(deg, rowp, bsums, N);
    k_scan_tail<<<nb, 1024, 0, stream>>>(rowp, bsums, fillp, N, nb);
    k_fill<<<2048, 256, 0, stream>>>(ei, E, fillp, colx, npr);

    // persistent fused pipeline: gemm_in + 3 x (agg, gemm)
    k_mega<<<512, 256, 0, stream>>>(
        xf, WtI_hi, WtI_lo, WtS_hi, WtS_lo, WtN_hi, WtN_lo,
        b_in, b_self, rowp, colx,
        hRowA, hfA, hRowB, hfB, Sf, out, N, L, cnt);
}

// Round 5
// 735.299 us; speedup vs baseline: 1.1093x; 1.1093x over previous
//
#include <hip/hip_runtime.h>
#include <cstdint>

#define HIDDEN 128

typedef unsigned short u16;
using frag_t   = __attribute__((ext_vector_type(8))) short;   // 8 bf16 (4 VGPRs)
using f32x4_t  = __attribute__((ext_vector_type(4))) float;   // MFMA accumulator
using ushort8_t = __attribute__((ext_vector_type(8))) unsigned short;

__device__ __forceinline__ float bf2f(u16 u) {
    union { unsigned int i; float f; } c;
    c.i = ((unsigned int)u) << 16;
    return c.f;
}
__device__ __forceinline__ u16 f2bf(float f) {
    unsigned int u = __float_as_uint(f);
    unsigned int r = (u + 0x7fffu + ((u >> 16) & 1u)) >> 16;   // RNE
    return (u16)r;
}

// ---------------- software grid barrier (all blocks co-resident by capacity) ----------------
// monotonic counter, increasing targets; cnt zeroed by host memset each launch.
// CRITICAL: poll with RELAXED loads (agent-acquire each poll = buffer_inv storm that
// invalidates every XCD's L2 continuously — measured 3.75x slowdown in round 4).
// One acquire fence after exit + one release writeback at arrival = kernel-boundary cost.
__device__ __forceinline__ void gbar(int* cnt, int target) {
    __syncthreads();
    if (threadIdx.x == 0) {
        __threadfence();   // push this block's writes to coherence point
        __hip_atomic_fetch_add(cnt, 1, __ATOMIC_RELEASE, __HIP_MEMORY_SCOPE_AGENT);
        while (__hip_atomic_load(cnt, __ATOMIC_RELAXED, __HIP_MEMORY_SCOPE_AGENT) < target)
            __builtin_amdgcn_s_sleep(2);
        __builtin_amdgcn_fence(__ATOMIC_ACQUIRE, "agent");   // single L1/L2 invalidate
    }
    __syncthreads();
}

// ---------------- CSR build + prep fused (edge_index arrives as int32 from harness) ----------------
// XCD-range partitioning: blocks with blockIdx&7==r own dst range [r*npr, (r+1)*npr).

__global__ void k_hist_prep(const int* __restrict__ ei, int E, int* __restrict__ deg, int npr,
                            const float* __restrict__ x,
                            const float* __restrict__ W_in,
                            const float* __restrict__ W_self,
                            const float* __restrict__ W_nbr,
                            u16* __restrict__ xf,
                            u16* __restrict__ WtI_hi, u16* __restrict__ WtI_lo,
                            u16* __restrict__ WtS_hi, u16* __restrict__ WtS_lo,
                            u16* __restrict__ WtN_hi, u16* __restrict__ WtN_lo,
                            int L, int nxg) {
    // ---- histogram part ----
    {
        int r  = blockIdx.x & 7;
        int lo = r * npr, hi = lo + npr;
        int nb = gridDim.x >> 3;
        int bi = blockIdx.x >> 3;
        int tid = bi * blockDim.x + threadIdx.x;
        int stride = nb * blockDim.x;
        if ((E & 3) == 0) {
            const int4* d4 = (const int4*)(ei + E);
            int nch = E >> 2;
            for (int c = tid; c < nch; c += stride) {
                int4 d = d4[c];
                if (d.x >= lo && d.x < hi) atomicAdd(&deg[d.x], 1);
                if (d.y >= lo && d.y < hi) atomicAdd(&deg[d.y], 1);
                if (d.z >= lo && d.z < hi) atomicAdd(&deg[d.z], 1);
                if (d.w >= lo && d.w < hi) atomicAdd(&deg[d.w], 1);
            }
        } else {
            for (int e = tid; e < E; e += stride) {
                int d = ei[E + e];
                if (d >= lo && d < hi) atomicAdd(&deg[d], 1);
            }
        }
    }
    // ---- prep part ----
    {
        int nIn = 64 * 128;
        int nSq = L * 128 * 128;
        int wtot = nIn + 2 * nSq;
        int total = wtot + nxg;
        int stride = gridDim.x * blockDim.x;
        for (int i = blockIdx.x * blockDim.x + threadIdx.x; i < total; i += stride) {
            if (i >= wtot) {
                int t = i - wtot;
                int row = t >> 3, c = t & 7;
                const float4* xs = (const float4*)(x + (size_t)row * 64 + c * 8);
                float4 v0 = xs[0], v1 = xs[1];
                ushort8_t o;
                o[0] = f2bf(v0.x); o[1] = f2bf(v0.y); o[2] = f2bf(v0.z); o[3] = f2bf(v0.w);
                o[4] = f2bf(v1.x); o[5] = f2bf(v1.y); o[6] = f2bf(v1.z); o[7] = f2bf(v1.w);
                int T = row >> 4, m = row & 15;
                int f = c >> 2, q = c & 3;
                *(ushort8_t*)&xf[((size_t)(T * 2 + f) * 64 + q * 16 + m) * 8] = o;
            } else {
                float v; u16* phi; u16* plo; int o;
                if (i < nIn) {
                    int n = i / 64, k = i % 64;
                    v = W_in[k * 128 + n]; phi = WtI_hi; plo = WtI_lo; o = n * 64 + k;
                } else if (i < nIn + nSq) {
                    int t = i - nIn;
                    int l = t / (128 * 128), r = t % (128 * 128);
                    int n = r / 128, k = r % 128;
                    v = W_self[l * 128 * 128 + k * 128 + n]; phi = WtS_hi; plo = WtS_lo;
                    o = l * 128 * 128 + n * 128 + k;
                } else {
                    int t = i - nIn - nSq;
                    int l = t / (128 * 128), r = t % (128 * 128);
                    int n = r / 128, k = r % 128;
                    v = W_nbr[l * 128 * 128 + k * 128 + n]; phi = WtN_hi; plo = WtN_lo;
                    o = l * 128 * 128 + n * 128 + k;
                }
                u16 hi = f2bf(v);
                phi[o] = hi;
                plo[o] = f2bf(v - bf2f(hi));
            }
        }
    }
}

__global__ void k_scan1(const int* __restrict__ deg, int* __restrict__ rowp,
                        int* __restrict__ bsums, int n) {
    __shared__ int sh[1024];
    int t = threadIdx.x;
    int base = blockIdx.x * 1024;
    int v = (base + t < n) ? deg[base + t] : 0;
    sh[t] = v;
    __syncthreads();
    for (int off = 1; off < 1024; off <<= 1) {
        int x = sh[t];
        int y = (t >= off) ? sh[t - off] : 0;
        __syncthreads();
        sh[t] = x + y;
        __syncthreads();
    }
    if (base + t < n) rowp[base + t + 1] = sh[t];
    if (t == 1023) bsums[blockIdx.x] = sh[1023];
}

// merged scan2+scan3: each block locally re-scans bsums in LDS, applies offset, writes fillp.
__global__ void k_scan_tail(int* __restrict__ rowp, const int* __restrict__ bsums,
                            int* __restrict__ fillp, int n, int nb) {
    __shared__ int sh[1024];
    int t = threadIdx.x;
    int b = blockIdx.x;
    sh[t] = (t < nb) ? bsums[t] : 0;
    __syncthreads();
    for (int off = 1; off < 1024; off <<= 1) {
        int x = sh[t];
        int y = (t >= off) ? sh[t - off] : 0;
        __syncthreads();
        sh[t] = x + y;
        __syncthreads();
    }
    int boff = (b == 0) ? 0 : sh[b - 1];
    int base = b * 1024;
    if (base + t < n) {
        int v = rowp[base + t + 1] + boff;
        rowp[base + t + 1] = v;
        if (base + t + 1 < n) fillp[base + t + 1] = v;
    }
    if (b == 0 && t == 0) { rowp[0] = 0; fillp[0] = 0; }
}

__global__ void k_fill(const int* __restrict__ ei, int E,
                       int* __restrict__ fillpos, int* __restrict__ colx, int npr) {
    int r  = blockIdx.x & 7;
    int lo = r * npr, hi = lo + npr;
    int nb = gridDim.x >> 3;
    int bi = blockIdx.x >> 3;
    int tid = bi * blockDim.x + threadIdx.x;
    int stride = nb * blockDim.x;
    if ((E & 3) == 0) {
        const int4* s4 = (const int4*)ei;
        const int4* d4 = (const int4*)(ei + E);
        int nch = E >> 2;
        for (int c = tid; c < nch; c += stride) {
            int4 d = d4[c];
            bool m0 = d.x >= lo && d.x < hi;
            bool m1 = d.y >= lo && d.y < hi;
            bool m2 = d.z >= lo && d.z < hi;
            bool m3 = d.w >= lo && d.w < hi;
            if (m0 | m1 | m2 | m3) {
                int4 s = s4[c];
                if (m0) colx[atomicAdd(&fillpos[d.x], 1)] = s.x;
                if (m1) colx[atomicAdd(&fillpos[d.y], 1)] = s.y;
                if (m2) colx[atomicAdd(&fillpos[d.z], 1)] = s.z;
                if (m3) colx[atomicAdd(&fillpos[d.w], 1)] = s.w;
            }
        }
    } else {
        for (int e = tid; e < E; e += stride) {
            int d = ei[E + e];
            if (d >= lo && d < hi) colx[atomicAdd(&fillpos[d], 1)] = ei[e];
        }
    }
}

// ---------------- device phase: aggregation (grid-stride, 16 outstanding gathers) ----------------
// accumulate order of the 16-chunk == two consecutive old 8-chunks -> bit-identical numerics.

__device__ __forceinline__ void dev_agg(const ushort8_t* __restrict__ hb8,
                                        const int* __restrict__ rowp,
                                        const int* __restrict__ colx,
                                        u16* __restrict__ Sf, int n) {
    int lane = threadIdx.x & 15;
    int ngr = (gridDim.x * blockDim.x) >> 4;
    for (int g = (blockIdx.x * blockDim.x + threadIdx.x) >> 4; g < n; g += ngr) {
        int beg = rowp[g];
        int end = rowp[g + 1];
        float a0[8], a1[8];
#pragma unroll
        for (int j = 0; j < 8; ++j) { a0[j] = 0.f; a1[j] = 0.f; }
        int e = beg;
        for (; e + 15 < end; e += 16) {
            int s0 = colx[e],      s1 = colx[e + 1],  s2 = colx[e + 2],  s3 = colx[e + 3];
            int s4 = colx[e + 4],  s5 = colx[e + 5],  s6 = colx[e + 6],  s7 = colx[e + 7];
            int s8 = colx[e + 8],  s9 = colx[e + 9],  sa = colx[e + 10], sb = colx[e + 11];
            int sc = colx[e + 12], sd = colx[e + 13], se = colx[e + 14], sf = colx[e + 15];
            ushort8_t v0 = hb8[(size_t)s0 * 16 + lane];
            ushort8_t v1 = hb8[(size_t)s1 * 16 + lane];
            ushort8_t v2 = hb8[(size_t)s2 * 16 + lane];
            ushort8_t v3 = hb8[(size_t)s3 * 16 + lane];
            ushort8_t v4 = hb8[(size_t)s4 * 16 + lane];
            ushort8_t v5 = hb8[(size_t)s5 * 16 + lane];
            ushort8_t v6 = hb8[(size_t)s6 * 16 + lane];
            ushort8_t v7 = hb8[(size_t)s7 * 16 + lane];
            ushort8_t v8 = hb8[(size_t)s8 * 16 + lane];
            ushort8_t v9 = hb8[(size_t)s9 * 16 + lane];
            ushort8_t va = hb8[(size_t)sa * 16 + lane];
            ushort8_t vb = hb8[(size_t)sb * 16 + lane];
            ushort8_t vc = hb8[(size_t)sc * 16 + lane];
            ushort8_t vd = hb8[(size_t)sd * 16 + lane];
            ushort8_t ve = hb8[(size_t)se * 16 + lane];
            ushort8_t vf = hb8[(size_t)sf * 16 + lane];
#pragma unroll
            for (int j = 0; j < 8; ++j) {
                a0[j] += bf2f(v0[j]); a1[j] += bf2f(v1[j]);
                a0[j] += bf2f(v2[j]); a1[j] += bf2f(v3[j]);
                a0[j] += bf2f(v4[j]); a1[j] += bf2f(v5[j]);
                a0[j] += bf2f(v6[j]); a1[j] += bf2f(v7[j]);
            }
#pragma unroll
            for (int j = 0; j < 8; ++j) {
                a0[j] += bf2f(v8[j]); a1[j] += bf2f(v9[j]);
                a0[j] += bf2f(va[j]); a1[j] += bf2f(vb[j]);
                a0[j] += bf2f(vc[j]); a1[j] += bf2f(vd[j]);
                a0[j] += bf2f(ve[j]); a1[j] += bf2f(vf[j]);
            }
        }
        for (; e + 7 < end; e += 8) {
            int s0 = colx[e],     s1 = colx[e + 1], s2 = colx[e + 2], s3 = colx[e + 3];
            int s4 = colx[e + 4], s5 = colx[e + 5], s6 = colx[e + 6], s7 = colx[e + 7];
            ushort8_t v0 = hb8[(size_t)s0 * 16 + lane];
            ushort8_t v1 = hb8[(size_t)s1 * 16 + lane];
            ushort8_t v2 = hb8[(size_t)s2 * 16 + lane];
            ushort8_t v3 = hb8[(size_t)s3 * 16 + lane];
            ushort8_t v4 = hb8[(size_t)s4 * 16 + lane];
            ushort8_t v5 = hb8[(size_t)s5 * 16 + lane];
            ushort8_t v6 = hb8[(size_t)s6 * 16 + lane];
            ushort8_t v7 = hb8[(size_t)s7 * 16 + lane];
#pragma unroll
            for (int j = 0; j < 8; ++j) {
                a0[j] += bf2f(v0[j]); a1[j] += bf2f(v1[j]);
                a0[j] += bf2f(v2[j]); a1[j] += bf2f(v3[j]);
                a0[j] += bf2f(v4[j]); a1[j] += bf2f(v5[j]);
                a0[j] += bf2f(v6[j]); a1[j] += bf2f(v7[j]);
            }
        }
        for (; e + 3 < end; e += 4) {
            int s0 = colx[e], s1 = colx[e + 1], s2 = colx[e + 2], s3 = colx[e + 3];
            ushort8_t v0 = hb8[(size_t)s0 * 16 + lane];
            ushort8_t v1 = hb8[(size_t)s1 * 16 + lane];
            ushort8_t v2 = hb8[(size_t)s2 * 16 + lane];
            ushort8_t v3 = hb8[(size_t)s3 * 16 + lane];
#pragma unroll
            for (int j = 0; j < 8; ++j) {
                a0[j] += bf2f(v0[j]); a1[j] += bf2f(v1[j]);
                a0[j] += bf2f(v2[j]); a1[j] += bf2f(v3[j]);
            }
        }
        for (; e < end; ++e) {
            int s = colx[e];
            ushort8_t v = hb8[(size_t)s * 16 + lane];
#pragma unroll
            for (int j = 0; j < 8; ++j) a0[j] += bf2f(v[j]);
        }
        int deg = end - beg;
        float inv = 1.0f / (float)(deg > 1 ? deg : 1);
        ushort8_t o;
#pragma unroll
        for (int j = 0; j < 8; ++j) o[j] = f2bf((a0[j] + a1[j]) * inv);
        int T = g >> 4, m = g & 15;
        *(ushort8_t*)&Sf[((size_t)(T * 4 + (lane >> 2)) * 64 + (lane & 3) * 16 + m) * 8] = o;
    }
}

// ---------------- device phase: MFMA GEMM (body identical to round-3 k_gemm_mfma) ----------------

template <int KF1, int KF2, int DO_ELU>
__device__ __forceinline__ void dev_gemm(
    const u16* __restrict__ A1f, const u16* __restrict__ A2f,
    const u16* __restrict__ B1h, const u16* __restrict__ B1l,
    const u16* __restrict__ B2h, const u16* __restrict__ B2l,
    const float* __restrict__ bias, float* __restrict__ C,
    u16* __restrict__ Hrow, u16* __restrict__ Hf,
    int M)
{
    constexpr int K1 = KF1 * 32;
    constexpr int K2 = KF2 * 32;
    constexpr int KF = KF1 + KF2;
    int lane = threadIdx.x & 63;
    int w    = threadIdx.x >> 6;
    int m16  = lane & 15;
    int quad = lane >> 4;
    int kq   = quad * 8;
    int ng   = (blockIdx.x >> 3) & 1;
    int mtb  = (blockIdx.x & 7) | ((blockIdx.x >> 4) << 3);   // [0, gridDim/2)
    int ncol = (ng * 4 + w) * 16 + m16;

    frag_t bh[KF], bl[KF];
    if constexpr (KF1 > 0) {
#pragma unroll
        for (int f = 0; f < KF1; ++f) {
            bh[f] = *(const frag_t*)&B1h[(size_t)ncol * K1 + f * 32 + kq];
            bl[f] = *(const frag_t*)&B1l[(size_t)ncol * K1 + f * 32 + kq];
        }
    }
    if constexpr (KF2 > 0) {
#pragma unroll
        for (int f = 0; f < KF2; ++f) {
            bh[KF1 + f] = *(const frag_t*)&B2h[(size_t)ncol * K2 + f * 32 + kq];
            bl[KF1 + f] = *(const frag_t*)&B2l[(size_t)ncol * K2 + f * 32 + kq];
        }
    }

    float bv = bias[ncol];
    int nMT  = (M + 31) >> 5;
    int step = gridDim.x >> 1;
    int fcol = ncol >> 5;
    int qcol = (ncol & 31) >> 3;
    int jcol = ncol & 7;

    auto loadA = [&](int mt, frag_t (&a0)[KF], frag_t (&a1)[KF]) {
        int T0 = mt * 2, T1 = T0 + 1;   // padded alloc: no guards
        if constexpr (KF1 > 0) {
#pragma unroll
            for (int f = 0; f < KF1; ++f) {
                a0[f] = *(const frag_t*)&A1f[((size_t)(T0 * KF1 + f) * 64 + lane) * 8];
                a1[f] = *(const frag_t*)&A1f[((size_t)(T1 * KF1 + f) * 64 + lane) * 8];
            }
        }
        if constexpr (KF2 > 0) {
#pragma unroll
            for (int f = 0; f < KF2; ++f) {
                a0[KF1 + f] = *(const frag_t*)&A2f[((size_t)(T0 * KF2 + f) * 64 + lane) * 8];
                a1[KF1 + f] = *(const frag_t*)&A2f[((size_t)(T1 * KF2 + f) * 64 + lane) * 8];
            }
        }
    };

    auto compute = [&](int mt, frag_t (&a0)[KF], frag_t (&a1)[KF]) {
        f32x4_t acc0 = (f32x4_t){0.f, 0.f, 0.f, 0.f};
        f32x4_t acc1 = (f32x4_t){0.f, 0.f, 0.f, 0.f};
#pragma unroll
        for (int f = 0; f < KF; ++f) {
            acc0 = __builtin_amdgcn_mfma_f32_16x16x32_bf16(a0[f], bh[f], acc0, 0, 0, 0);
            acc1 = __builtin_amdgcn_mfma_f32_16x16x32_bf16(a1[f], bh[f], acc1, 0, 0, 0);
            acc0 = __builtin_amdgcn_mfma_f32_16x16x32_bf16(a0[f], bl[f], acc0, 0, 0, 0);
            acc1 = __builtin_amdgcn_mfma_f32_16x16x32_bf16(a1[f], bl[f], acc1, 0, 0, 0);
        }
        int rb = mt * 32 + quad * 4;
#pragma unroll
        for (int r = 0; r < 4; ++r) {
#pragma unroll
            for (int half = 0; half < 2; ++half) {
                int row = rb + r + half * 16;
                float av = half ? acc1[r] : acc0[r];
                if (row < M) {
                    float v = av + bv;
                    if constexpr (DO_ELU) v = (v > 0.f) ? v : expm1f(v);
                    if (C) C[(size_t)row * HIDDEN + ncol] = v;
                    if (Hrow) {
                        u16 hv = f2bf(v);
                        Hrow[(size_t)row * HIDDEN + ncol] = hv;
                        Hf[((size_t)((row >> 4) * 4 + fcol) * 64 + qcol * 16 + (row & 15)) * 8 + jcol] = hv;
                    }
                }
            }
        }
    };

    int mt = mtb;
    if (mt < nMT) {     // guarded skip (no return: barriers follow in caller)
        frag_t xa0[KF], xa1[KF], ya0[KF], ya1[KF];
        loadA(mt, xa0, xa1);
        while (true) {
            int mt2 = mt + step;
            if (mt2 < nMT) loadA(mt2, ya0, ya1);       // prefetch under compute(mt)
            compute(mt, xa0, xa1);
            if (mt2 >= nMT) break;
            int mt3 = mt2 + step;
            if (mt3 < nMT) loadA(mt3, xa0, xa1);       // prefetch under compute(mt2)
            compute(mt2, ya0, ya1);
            if (mt3 >= nMT) break;
            mt = mt3;
        }
    }
}

// ---------------- persistent mega-kernel: gemm_in + L x (agg, gemm) with grid barriers ----
// grid = 512 blocks x 256 thr, __launch_bounds__(256,2) => exactly 2 blocks/CU on 256 CUs:
// all blocks co-resident by capacity => software barrier is safe.

__global__ __launch_bounds__(256, 2) void k_mega(
    const u16* __restrict__ xf,
    const u16* __restrict__ WtI_hi, const u16* __restrict__ WtI_lo,
    const u16* __restrict__ WtS_hi, const u16* __restrict__ WtS_lo,
    const u16* __restrict__ WtN_hi, const u16* __restrict__ WtN_lo,
    const float* __restrict__ b_in, const float* __restrict__ b_self,
    const int* __restrict__ rowp, const int* __restrict__ colx,
    u16* __restrict__ hRowA, u16* __restrict__ hfA,
    u16* __restrict__ hRowB, u16* __restrict__ hfB,
    u16* __restrict__ Sf,
    float* __restrict__ out,
    int N, int L, int* __restrict__ cnt)
{
    int nb = gridDim.x;
    int bt = nb;

    // P0: input projection  h = bf16(x @ W_in + b_in)
    dev_gemm<2, 0, 0>(xf, nullptr, WtI_hi, WtI_lo, nullptr, nullptr,
                      b_in, nullptr, hRowA, hfA, N);
    gbar(cnt, bt); bt += nb;

    u16* curRow = hRowA; u16* curF = hfA;
    u16* nxtRow = hRowB; u16* nxtF = hfB;

    for (int l = 0; l < L; ++l) {
        dev_agg((const ushort8_t*)curRow, rowp, colx, Sf, N);
        gbar(cnt, bt); bt += nb;

        const u16* Wsh = WtS_hi + (size_t)l * 128 * 128;
        const u16* Wsl = WtS_lo + (size_t)l * 128 * 128;
        const u16* Wnh = WtN_hi + (size_t)l * 128 * 128;
        const u16* Wnl = WtN_lo + (size_t)l * 128 * 128;
        const float* bs = b_self + (size_t)l * HIDDEN;
        bool last = (l == L - 1);
        dev_gemm<4, 4, 1>(curF, Sf, Wsh, Wsl, Wnh, Wnl, bs,
                          last ? out : nullptr,
                          last ? nullptr : nxtRow, last ? nullptr : nxtF, N);
        if (!last) {
            gbar(cnt, bt); bt += nb;
            u16* tr = curRow; curRow = nxtRow; nxtRow = tr;
            u16* tf = curF;   curF = nxtF;     nxtF = tf;
        }
    }
}

// ---------------- launch ----------------

extern "C" void kernel_launch(void* const* d_in, const int* in_sizes, int n_in,
                              void* d_out, int out_size, void* d_ws, size_t ws_size,
                              hipStream_t stream) {
    const float* x        = (const float*)d_in[0];
    const int* ei         = (const int*)d_in[1];
    const float* W_in     = (const float*)d_in[2];
    const float* b_in     = (const float*)d_in[3];
    const float* W_self   = (const float*)d_in[4];
    const float* b_self   = (const float*)d_in[5];
    const float* W_nbr    = (const float*)d_in[6];
    float* out = (float*)d_out;

    const int IN_FEAT = 64;
    int N = in_sizes[0] / IN_FEAT;           // 50000
    int E = in_sizes[1] / 2;                 // 800000
    int L = in_sizes[4] / (HIDDEN * HIDDEN); // 3

    char* ws = (char*)d_ws;
    size_t off = 0;
    auto alloc = [&](size_t bytes) -> void* {
        void* p = ws + off;
        off = (off + bytes + 255) & ~(size_t)255;
        return p;
    };

    int nT = ((N + 31) / 32) * 2;            // 16-row tiles, padded to macro-tile pairs

    u16* hRowA = (u16*)alloc((size_t)N * HIDDEN * 2);
    u16* hRowB = (u16*)alloc((size_t)N * HIDDEN * 2);
    u16* hfA   = (u16*)alloc((size_t)nT * 4 * 64 * 8 * 2);   // KF=4 frag-major
    u16* hfB   = (u16*)alloc((size_t)nT * 4 * 64 * 8 * 2);
    u16* xf    = (u16*)alloc((size_t)nT * 2 * 64 * 8 * 2);   // KF=2
    u16* Sf    = (u16*)alloc((size_t)nT * 4 * 64 * 8 * 2);
    u16* WtI_hi = (u16*)alloc(128 * 64 * 2);
    u16* WtI_lo = (u16*)alloc(128 * 64 * 2);
    u16* WtS_hi = (u16*)alloc((size_t)L * 128 * 128 * 2);
    u16* WtS_lo = (u16*)alloc((size_t)L * 128 * 128 * 2);
    u16* WtN_hi = (u16*)alloc((size_t)L * 128 * 128 * 2);
    u16* WtN_lo = (u16*)alloc((size_t)L * 128 * 128 * 2);
    int* deg   = (int*)alloc((size_t)(N + 64) * sizeof(int));   // +cnt tail (zeroed together)
    int* cnt   = deg + N;
    int* rowp  = (int*)alloc((size_t)(N + 1) * sizeof(int));
    int* fillp = (int*)alloc((size_t)N * sizeof(int));
    int* colx  = (int*)alloc((size_t)E * sizeof(int));
    int* bsums = (int*)alloc(1024 * sizeof(int));

    int npr = (N + 7) / 8;   // nodes per XCD range

    // CSR build (XCD-range-partitioned scatters) with prep fused into hist; zeroes cnt too
    hipMemsetAsync(deg, 0, (size_t)(N + 64) * sizeof(int), stream);
    k_hist_prep<<<2048, 256, 0, stream>>>(ei, E, deg, npr,
                                          x, W_in, W_self, W_nbr, xf,
                                          WtI_hi, WtI_lo, WtS_hi, WtS_lo,
                                          WtN_hi, WtN_lo, L, N * 8);
    int nb = (N + 1023) / 1024;
    k_scan1<<<nb, 1024, 0, stream>>>(deg, rowp, bsums, N);
    k_scan_tail<<<nb, 1024, 0, stream>>>(rowp, bsums, fillp, N, nb);
    k_fill<<<2048, 256, 0, stream>>>(ei, E, fillp, colx, npr);

    // persistent fused pipeline: gemm_in + 3 x (agg, gemm)
    k_mega<<<512, 256, 0, stream>>>(
        xf, WtI_hi, WtI_lo, WtS_hi, WtS_lo, WtN_hi, WtN_lo,
        b_in, b_self, rowp, colx,
        hRowA, hfA, hRowB, hfB, Sf, out, N, L, cnt);
}

// Round 6
// 379.387 us; speedup vs baseline: 2.1500x; 1.9381x over previous
//
#include <hip/hip_runtime.h>
#include <cstdint>

#define HIDDEN 128

typedef unsigned short u16;
using frag_t   = __attribute__((ext_vector_type(8))) short;   // 8 bf16 (4 VGPRs)
using f32x4_t  = __attribute__((ext_vector_type(4))) float;   // MFMA accumulator
using ushort8_t = __attribute__((ext_vector_type(8))) unsigned short;

__device__ __forceinline__ float bf2f(u16 u) {
    union { unsigned int i; float f; } c;
    c.i = ((unsigned int)u) << 16;
    return c.f;
}
__device__ __forceinline__ u16 f2bf(float f) {
    unsigned int u = __float_as_uint(f);
    unsigned int r = (u + 0x7fffu + ((u >> 16) & 1u)) >> 16;   // RNE
    return (u16)r;
}

// ---------------- CSR build + weight prep fused ----------------
// XCD-range partitioning: blocks with blockIdx&7==r own dst range [r*npr, (r+1)*npr).

__global__ void k_hist_wprep(const int* __restrict__ ei, int E, int* __restrict__ deg, int npr,
                             const float* __restrict__ W_in,
                             const float* __restrict__ W_self,
                             const float* __restrict__ W_nbr,
                             u16* __restrict__ WtI_hi, u16* __restrict__ WtI_lo,
                             u16* __restrict__ WtS_hi, u16* __restrict__ WtS_lo,
                             u16* __restrict__ WtN_hi, u16* __restrict__ WtN_lo,
                             int L) {
    // ---- histogram part ----
    {
        int r  = blockIdx.x & 7;
        int lo = r * npr, hi = lo + npr;
        int nb = gridDim.x >> 3;
        int bi = blockIdx.x >> 3;
        int tid = bi * blockDim.x + threadIdx.x;
        int stride = nb * blockDim.x;
        if ((E & 3) == 0) {
            const int4* d4 = (const int4*)(ei + E);
            int nch = E >> 2;
            for (int c = tid; c < nch; c += stride) {
                int4 d = d4[c];
                if (d.x >= lo && d.x < hi) atomicAdd(&deg[d.x], 1);
                if (d.y >= lo && d.y < hi) atomicAdd(&deg[d.y], 1);
                if (d.z >= lo && d.z < hi) atomicAdd(&deg[d.z], 1);
                if (d.w >= lo && d.w < hi) atomicAdd(&deg[d.w], 1);
            }
        } else {
            for (int e = tid; e < E; e += stride) {
                int d = ei[E + e];
                if (d >= lo && d < hi) atomicAdd(&deg[d], 1);
            }
        }
    }
    // ---- weight prep: transpose + fp32 -> bf16 hi/lo, layout Wt[n][k] ----
    {
        int nIn = 64 * 128;
        int nSq = L * 128 * 128;
        int wtot = nIn + 2 * nSq;
        int stride = gridDim.x * blockDim.x;
        for (int i = blockIdx.x * blockDim.x + threadIdx.x; i < wtot; i += stride) {
            float v; u16* phi; u16* plo; int o;
            if (i < nIn) {
                int n = i / 64, k = i % 64;
                v = W_in[k * 128 + n]; phi = WtI_hi; plo = WtI_lo; o = n * 64 + k;
            } else if (i < nIn + nSq) {
                int t = i - nIn;
                int l = t / (128 * 128), r = t % (128 * 128);
                int n = r / 128, k = r % 128;
                v = W_self[l * 128 * 128 + k * 128 + n]; phi = WtS_hi; plo = WtS_lo;
                o = l * 128 * 128 + n * 128 + k;
            } else {
                int t = i - nIn - nSq;
                int l = t / (128 * 128), r = t % (128 * 128);
                int n = r / 128, k = r % 128;
                v = W_nbr[l * 128 * 128 + k * 128 + n]; phi = WtN_hi; plo = WtN_lo;
                o = l * 128 * 128 + n * 128 + k;
            }
            u16 hi = f2bf(v);
            phi[o] = hi;
            plo[o] = f2bf(v - bf2f(hi));
        }
    }
}

__global__ void k_scan1(const int* __restrict__ deg, int* __restrict__ rowp,
                        int* __restrict__ bsums, int n) {
    __shared__ int sh[1024];
    int t = threadIdx.x;
    int base = blockIdx.x * 1024;
    int v = (base + t < n) ? deg[base + t] : 0;
    sh[t] = v;
    __syncthreads();
    for (int off = 1; off < 1024; off <<= 1) {
        int x = sh[t];
        int y = (t >= off) ? sh[t - off] : 0;
        __syncthreads();
        sh[t] = x + y;
        __syncthreads();
    }
    if (base + t < n) rowp[base + t + 1] = sh[t];
    if (t == 1023) bsums[blockIdx.x] = sh[1023];
}

// merged scan2+scan3: each block locally re-scans bsums in LDS, applies offset, writes fillp.
__global__ void k_scan_tail(int* __restrict__ rowp, const int* __restrict__ bsums,
                            int* __restrict__ fillp, int n, int nb) {
    __shared__ int sh[1024];
    int t = threadIdx.x;
    int b = blockIdx.x;
    sh[t] = (t < nb) ? bsums[t] : 0;
    __syncthreads();
    for (int off = 1; off < 1024; off <<= 1) {
        int x = sh[t];
        int y = (t >= off) ? sh[t - off] : 0;
        __syncthreads();
        sh[t] = x + y;
        __syncthreads();
    }
    int boff = (b == 0) ? 0 : sh[b - 1];
    int base = b * 1024;
    if (base + t < n) {
        int v = rowp[base + t + 1] + boff;
        rowp[base + t + 1] = v;
        if (base + t + 1 < n) fillp[base + t + 1] = v;
    }
    if (b == 0 && t == 0) { rowp[0] = 0; fillp[0] = 0; }
}

__global__ void k_fill(const int* __restrict__ ei, int E,
                       int* __restrict__ fillpos, int* __restrict__ colx, int npr) {
    int r  = blockIdx.x & 7;
    int lo = r * npr, hi = lo + npr;
    int nb = gridDim.x >> 3;
    int bi = blockIdx.x >> 3;
    int tid = bi * blockDim.x + threadIdx.x;
    int stride = nb * blockDim.x;
    if ((E & 3) == 0) {
        const int4* s4 = (const int4*)ei;
        const int4* d4 = (const int4*)(ei + E);
        int nch = E >> 2;
        for (int c = tid; c < nch; c += stride) {
            int4 d = d4[c];
            bool m0 = d.x >= lo && d.x < hi;
            bool m1 = d.y >= lo && d.y < hi;
            bool m2 = d.z >= lo && d.z < hi;
            bool m3 = d.w >= lo && d.w < hi;
            if (m0 | m1 | m2 | m3) {
                int4 s = s4[c];
                if (m0) colx[atomicAdd(&fillpos[d.x], 1)] = s.x;
                if (m1) colx[atomicAdd(&fillpos[d.y], 1)] = s.y;
                if (m2) colx[atomicAdd(&fillpos[d.z], 1)] = s.z;
                if (m3) colx[atomicAdd(&fillpos[d.w], 1)] = s.w;
            }
        }
    } else {
        for (int e = tid; e < E; e += stride) {
            int d = ei[E + e];
            if (d >= lo && d < hi) colx[atomicAdd(&fillpos[d], 1)] = ei[e];
        }
    }
}

// ---------------- aggregation: S = bf16(mean over CSR row of hRow rows), ROW-MAJOR out ----
// 16 lanes/node, 16B gathers, 16 outstanding loads (order == two consecutive 8-chunks).

__global__ __launch_bounds__(256, 4) void k_agg(
        const ushort8_t* __restrict__ hb8, const int* __restrict__ rowp,
        const int* __restrict__ colx, u16* __restrict__ S, int n) {
    int g = (blockIdx.x * blockDim.x + threadIdx.x) >> 4;   // 16 lanes/node, lane = 8 cols
    int lane = threadIdx.x & 15;
    if (g >= n) return;
    int beg = rowp[g];
    int end = rowp[g + 1];
    float a0[8], a1[8];
#pragma unroll
    for (int j = 0; j < 8; ++j) { a0[j] = 0.f; a1[j] = 0.f; }
    int e = beg;
    for (; e + 15 < end; e += 16) {
        int s0 = colx[e],      s1 = colx[e + 1],  s2 = colx[e + 2],  s3 = colx[e + 3];
        int s4 = colx[e + 4],  s5 = colx[e + 5],  s6 = colx[e + 6],  s7 = colx[e + 7];
        int s8 = colx[e + 8],  s9 = colx[e + 9],  sa = colx[e + 10], sb = colx[e + 11];
        int sc = colx[e + 12], sd = colx[e + 13], se = colx[e + 14], sf = colx[e + 15];
        ushort8_t v0 = hb8[(size_t)s0 * 16 + lane];
        ushort8_t v1 = hb8[(size_t)s1 * 16 + lane];
        ushort8_t v2 = hb8[(size_t)s2 * 16 + lane];
        ushort8_t v3 = hb8[(size_t)s3 * 16 + lane];
        ushort8_t v4 = hb8[(size_t)s4 * 16 + lane];
        ushort8_t v5 = hb8[(size_t)s5 * 16 + lane];
        ushort8_t v6 = hb8[(size_t)s6 * 16 + lane];
        ushort8_t v7 = hb8[(size_t)s7 * 16 + lane];
        ushort8_t v8 = hb8[(size_t)s8 * 16 + lane];
        ushort8_t v9 = hb8[(size_t)s9 * 16 + lane];
        ushort8_t va = hb8[(size_t)sa * 16 + lane];
        ushort8_t vb = hb8[(size_t)sb * 16 + lane];
        ushort8_t vc = hb8[(size_t)sc * 16 + lane];
        ushort8_t vd = hb8[(size_t)sd * 16 + lane];
        ushort8_t ve = hb8[(size_t)se * 16 + lane];
        ushort8_t vf = hb8[(size_t)sf * 16 + lane];
#pragma unroll
        for (int j = 0; j < 8; ++j) {
            a0[j] += bf2f(v0[j]); a1[j] += bf2f(v1[j]);
            a0[j] += bf2f(v2[j]); a1[j] += bf2f(v3[j]);
            a0[j] += bf2f(v4[j]); a1[j] += bf2f(v5[j]);
            a0[j] += bf2f(v6[j]); a1[j] += bf2f(v7[j]);
        }
#pragma unroll
        for (int j = 0; j < 8; ++j) {
            a0[j] += bf2f(v8[j]); a1[j] += bf2f(v9[j]);
            a0[j] += bf2f(va[j]); a1[j] += bf2f(vb[j]);
            a0[j] += bf2f(vc[j]); a1[j] += bf2f(vd[j]);
            a0[j] += bf2f(ve[j]); a1[j] += bf2f(vf[j]);
        }
    }
    for (; e + 7 < end; e += 8) {
        int s0 = colx[e],     s1 = colx[e + 1], s2 = colx[e + 2], s3 = colx[e + 3];
        int s4 = colx[e + 4], s5 = colx[e + 5], s6 = colx[e + 6], s7 = colx[e + 7];
        ushort8_t v0 = hb8[(size_t)s0 * 16 + lane];
        ushort8_t v1 = hb8[(size_t)s1 * 16 + lane];
        ushort8_t v2 = hb8[(size_t)s2 * 16 + lane];
        ushort8_t v3 = hb8[(size_t)s3 * 16 + lane];
        ushort8_t v4 = hb8[(size_t)s4 * 16 + lane];
        ushort8_t v5 = hb8[(size_t)s5 * 16 + lane];
        ushort8_t v6 = hb8[(size_t)s6 * 16 + lane];
        ushort8_t v7 = hb8[(size_t)s7 * 16 + lane];
#pragma unroll
        for (int j = 0; j < 8; ++j) {
            a0[j] += bf2f(v0[j]); a1[j] += bf2f(v1[j]);
            a0[j] += bf2f(v2[j]); a1[j] += bf2f(v3[j]);
            a0[j] += bf2f(v4[j]); a1[j] += bf2f(v5[j]);
            a0[j] += bf2f(v6[j]); a1[j] += bf2f(v7[j]);
        }
    }
    for (; e + 3 < end; e += 4) {
        int s0 = colx[e], s1 = colx[e + 1], s2 = colx[e + 2], s3 = colx[e + 3];
        ushort8_t v0 = hb8[(size_t)s0 * 16 + lane];
        ushort8_t v1 = hb8[(size_t)s1 * 16 + lane];
        ushort8_t v2 = hb8[(size_t)s2 * 16 + lane];
        ushort8_t v3 = hb8[(size_t)s3 * 16 + lane];
#pragma unroll
        for (int j = 0; j < 8; ++j) {
            a0[j] += bf2f(v0[j]); a1[j] += bf2f(v1[j]);
            a0[j] += bf2f(v2[j]); a1[j] += bf2f(v3[j]);
        }
    }
    for (; e < end; ++e) {
        int s = colx[e];
        ushort8_t v = hb8[(size_t)s * 16 + lane];
#pragma unroll
        for (int j = 0; j < 8; ++j) a0[j] += bf2f(v[j]);
    }
    int deg = end - beg;
    float inv = 1.0f / (float)(deg > 1 ? deg : 1);
    ushort8_t o;
#pragma unroll
    for (int j = 0; j < 8; ++j) o[j] = f2bf((a0[j] + a1[j]) * inv);
    // row-major store: 16 lanes x 16B = 256B contiguous per node
    *(ushort8_t*)&S[(size_t)g * 128 + lane * 8] = o;
}

// ---------------- MFMA GEMM: ROW-MAJOR A (16B/lane, 16 full lines/instr), persistent B, prefetch ----
// A-frag for lane l: row = tile*16 + (l&15), k-bytes [f*32 + (l>>4)*8, +8) elements.
// A1F32: A1 is fp32 row-major (input x), converted to bf16 in-register at load.
// Padding rows clamp to M-1 (their outputs are guarded off -> numerics unaffected).

template <int KF1, int KF2, int DO_ELU, int A1F32>
__global__ __launch_bounds__(256, 2) void k_gemm_mfma(
    const void* __restrict__ A1v, const u16* __restrict__ A2,
    const u16* __restrict__ B1h, const u16* __restrict__ B1l,
    const u16* __restrict__ B2h, const u16* __restrict__ B2l,
    const float* __restrict__ bias, float* __restrict__ C,
    u16* __restrict__ Hrow, int M)
{
    constexpr int K1 = KF1 * 32;
    constexpr int K2 = KF2 * 32;
    constexpr int KF = KF1 + KF2;
    const u16*   A1b = (const u16*)A1v;
    const float* A1x = (const float*)A1v;
    int lane = threadIdx.x & 63;
    int w    = threadIdx.x >> 6;
    int m16  = lane & 15;
    int quad = lane >> 4;
    int kq   = quad * 8;
    int ng   = (blockIdx.x >> 3) & 1;
    int mtb  = (blockIdx.x & 7) | ((blockIdx.x >> 4) << 3);   // [0, gridDim/2)
    int ncol = (ng * 4 + w) * 16 + m16;     // this lane's output column (B row)

    frag_t bh[KF], bl[KF];
    if constexpr (KF1 > 0) {
#pragma unroll
        for (int f = 0; f < KF1; ++f) {
            bh[f] = *(const frag_t*)&B1h[(size_t)ncol * K1 + f * 32 + kq];
            bl[f] = *(const frag_t*)&B1l[(size_t)ncol * K1 + f * 32 + kq];
        }
    }
    if constexpr (KF2 > 0) {
#pragma unroll
        for (int f = 0; f < KF2; ++f) {
            bh[KF1 + f] = *(const frag_t*)&B2h[(size_t)ncol * K2 + f * 32 + kq];
            bl[KF1 + f] = *(const frag_t*)&B2l[(size_t)ncol * K2 + f * 32 + kq];
        }
    }

    float bv = bias[ncol];
    int nMT  = (M + 31) >> 5;
    int step = gridDim.x >> 1;

    auto loadA = [&](int mt, frag_t (&a0)[KF], frag_t (&a1)[KF]) {
        int r0 = mt * 32 + m16;
        int r1 = r0 + 16;
        r0 = r0 < M ? r0 : M - 1;   // clamp padding rows (outputs guarded)
        r1 = r1 < M ? r1 : M - 1;
        if constexpr (KF1 > 0) {
            if constexpr (A1F32) {
#pragma unroll
                for (int f = 0; f < KF1; ++f) {
                    const float* p0 = A1x + (size_t)r0 * K1 + f * 32 + kq;
                    const float* p1 = A1x + (size_t)r1 * K1 + f * 32 + kq;
                    float4 u0 = *(const float4*)p0;
                    float4 u1 = *(const float4*)(p0 + 4);
                    float4 w0 = *(const float4*)p1;
                    float4 w1 = *(const float4*)(p1 + 4);
                    frag_t t0, t1;
                    t0[0] = (short)f2bf(u0.x); t0[1] = (short)f2bf(u0.y);
                    t0[2] = (short)f2bf(u0.z); t0[3] = (short)f2bf(u0.w);
                    t0[4] = (short)f2bf(u1.x); t0[5] = (short)f2bf(u1.y);
                    t0[6] = (short)f2bf(u1.z); t0[7] = (short)f2bf(u1.w);
                    t1[0] = (short)f2bf(w0.x); t1[1] = (short)f2bf(w0.y);
                    t1[2] = (short)f2bf(w0.z); t1[3] = (short)f2bf(w0.w);
                    t1[4] = (short)f2bf(w1.x); t1[5] = (short)f2bf(w1.y);
                    t1[6] = (short)f2bf(w1.z); t1[7] = (short)f2bf(w1.w);
                    a0[f] = t0; a1[f] = t1;
                }
            } else {
#pragma unroll
                for (int f = 0; f < KF1; ++f) {
                    a0[f] = *(const frag_t*)&A1b[(size_t)r0 * K1 + f * 32 + kq];
                    a1[f] = *(const frag_t*)&A1b[(size_t)r1 * K1 + f * 32 + kq];
                }
            }
        }
        if constexpr (KF2 > 0) {
#pragma unroll
            for (int f = 0; f < KF2; ++f) {
                a0[KF1 + f] = *(const frag_t*)&A2[(size_t)r0 * K2 + f * 32 + kq];
                a1[KF1 + f] = *(const frag_t*)&A2[(size_t)r1 * K2 + f * 32 + kq];
            }
        }
    };

    auto compute = [&](int mt, frag_t (&a0)[KF], frag_t (&a1)[KF]) {
        f32x4_t acc0 = (f32x4_t){0.f, 0.f, 0.f, 0.f};
        f32x4_t acc1 = (f32x4_t){0.f, 0.f, 0.f, 0.f};
#pragma unroll
        for (int f = 0; f < KF; ++f) {
            acc0 = __builtin_amdgcn_mfma_f32_16x16x32_bf16(a0[f], bh[f], acc0, 0, 0, 0);
            acc1 = __builtin_amdgcn_mfma_f32_16x16x32_bf16(a1[f], bh[f], acc1, 0, 0, 0);
            acc0 = __builtin_amdgcn_mfma_f32_16x16x32_bf16(a0[f], bl[f], acc0, 0, 0, 0);
            acc1 = __builtin_amdgcn_mfma_f32_16x16x32_bf16(a1[f], bl[f], acc1, 0, 0, 0);
        }
        // epilogue: C/D layout col = lane&15, row = quad*4 + reg
        int rb = mt * 32 + quad * 4;
#pragma unroll
        for (int r = 0; r < 4; ++r) {
#pragma unroll
            for (int half = 0; half < 2; ++half) {
                int row = rb + r + half * 16;
                float av = half ? acc1[r] : acc0[r];
                if (row < M) {
                    float v = av + bv;
                    if constexpr (DO_ELU) v = (v > 0.f) ? v : expm1f(v);
                    if (C) C[(size_t)row * HIDDEN + ncol] = v;
                    if (Hrow) Hrow[(size_t)row * HIDDEN + ncol] = f2bf(v);
                }
            }
        }
    };

    int mt = mtb;
    if (mt >= nMT) return;
    frag_t xa0[KF], xa1[KF], ya0[KF], ya1[KF];
    loadA(mt, xa0, xa1);
    while (true) {
        int mt2 = mt + step;
        if (mt2 < nMT) loadA(mt2, ya0, ya1);       // prefetch under compute(mt)
        compute(mt, xa0, xa1);
        if (mt2 >= nMT) break;
        int mt3 = mt2 + step;
        if (mt3 < nMT) loadA(mt3, xa0, xa1);       // prefetch under compute(mt2)
        compute(mt2, ya0, ya1);
        if (mt3 >= nMT) break;
        mt = mt3;
    }
}

// ---------------- launch ----------------

extern "C" void kernel_launch(void* const* d_in, const int* in_sizes, int n_in,
                              void* d_out, int out_size, void* d_ws, size_t ws_size,
                              hipStream_t stream) {
    const float* x        = (const float*)d_in[0];
    const int* ei         = (const int*)d_in[1];
    const float* W_in     = (const float*)d_in[2];
    const float* b_in     = (const float*)d_in[3];
    const float* W_self   = (const float*)d_in[4];
    const float* b_self   = (const float*)d_in[5];
    const float* W_nbr    = (const float*)d_in[6];
    float* out = (float*)d_out;

    const int IN_FEAT = 64;
    int N = in_sizes[0] / IN_FEAT;           // 50000
    int E = in_sizes[1] / 2;                 // 800000
    int L = in_sizes[4] / (HIDDEN * HIDDEN); // 3

    char* ws = (char*)d_ws;
    size_t off = 0;
    auto alloc = [&](size_t bytes) -> void* {
        void* p = ws + off;
        off = (off + bytes + 255) & ~(size_t)255;
        return p;
    };

    // row-major activation buffers, padded by 32 rows (A-loads clamp; outputs guarded)
    u16* hRowA = (u16*)alloc((size_t)(N + 32) * HIDDEN * 2);
    u16* hRowB = (u16*)alloc((size_t)(N + 32) * HIDDEN * 2);
    u16* S     = (u16*)alloc((size_t)(N + 32) * HIDDEN * 2);
    u16* WtI_hi = (u16*)alloc(128 * 64 * 2);
    u16* WtI_lo = (u16*)alloc(128 * 64 * 2);
    u16* WtS_hi = (u16*)alloc((size_t)L * 128 * 128 * 2);
    u16* WtS_lo = (u16*)alloc((size_t)L * 128 * 128 * 2);
    u16* WtN_hi = (u16*)alloc((size_t)L * 128 * 128 * 2);
    u16* WtN_lo = (u16*)alloc((size_t)L * 128 * 128 * 2);
    int* deg   = (int*)alloc((size_t)N * sizeof(int));
    int* rowp  = (int*)alloc((size_t)(N + 1) * sizeof(int));
    int* fillp = (int*)alloc((size_t)N * sizeof(int));
    int* colx  = (int*)alloc((size_t)E * sizeof(int));
    int* bsums = (int*)alloc(1024 * sizeof(int));

    int npr = (N + 7) / 8;   // nodes per XCD range

    // CSR build (XCD-range-partitioned scatters) with weight prep fused into hist
    hipMemsetAsync(deg, 0, (size_t)N * sizeof(int), stream);
    k_hist_wprep<<<2048, 256, 0, stream>>>(ei, E, deg, npr,
                                           W_in, W_self, W_nbr,
                                           WtI_hi, WtI_lo, WtS_hi, WtS_lo,
                                           WtN_hi, WtN_lo, L);
    int nb = (N + 1023) / 1024;
    k_scan1<<<nb, 1024, 0, stream>>>(deg, rowp, bsums, N);
    k_scan_tail<<<nb, 1024, 0, stream>>>(rowp, bsums, fillp, N, nb);
    k_fill<<<2048, 256, 0, stream>>>(ei, E, fillp, colx, npr);

    const int GB = 1024;   // multiple of 16: ng=(b>>3)&1 XCD-paired; ~3 tiles/block for prefetch

    // input projection: h = bf16(x @ W_in + b_in)  (A = x fp32, converted in-register)
    k_gemm_mfma<2, 0, 0, 1><<<GB, 256, 0, stream>>>(
        x, nullptr,
        WtI_hi, WtI_lo, nullptr, nullptr,
        b_in, nullptr, hRowA, N);

    u16* curRow = hRowA;
    u16* nxtRow = hRowB;

    for (int l = 0; l < L; ++l) {
        k_agg<<<(N + 15) / 16, 256, 0, stream>>>((const ushort8_t*)curRow, rowp, colx, S, N);
        const u16* Wsh = WtS_hi + (size_t)l * 128 * 128;
        const u16* Wsl = WtS_lo + (size_t)l * 128 * 128;
        const u16* Wnh = WtN_hi + (size_t)l * 128 * 128;
        const u16* Wnl = WtN_lo + (size_t)l * 128 * 128;
        const float* bs = b_self + (size_t)l * HIDDEN;
        bool last = (l == L - 1);
        k_gemm_mfma<4, 4, 1, 0><<<GB, 256, 0, stream>>>(
            curRow, S,
            Wsh, Wsl, Wnh, Wnl,
            bs, last ? out : nullptr,
            last ? nullptr : nxtRow, N);
        u16* tr = curRow; curRow = nxtRow; nxtRow = tr;
    }
}

// Round 7
// 326.697 us; speedup vs baseline: 2.4968x; 1.1613x over previous
//
#include <hip/hip_runtime.h>
#include <cstdint>

#define HIDDEN 128

typedef unsigned short u16;
using frag_t   = __attribute__((ext_vector_type(8))) short;   // 8 bf16 (4 VGPRs)
using f32x4_t  = __attribute__((ext_vector_type(4))) float;   // MFMA accumulator
using ushort8_t = __attribute__((ext_vector_type(8))) unsigned short;

__device__ __forceinline__ float bf2f(u16 u) {
    union { unsigned int i; float f; } c;
    c.i = ((unsigned int)u) << 16;
    return c.f;
}
__device__ __forceinline__ u16 f2bf(float f) {
    unsigned int u = __float_as_uint(f);
    unsigned int r = (u + 0x7fffu + ((u >> 16) & 1u)) >> 16;   // RNE
    return (u16)r;
}

// ---------------- CSR build + prep fused (edge_index arrives as int32 from harness) ----------------
// XCD-range partitioning: blocks with blockIdx&7==r own dst range [r*npr, (r+1)*npr).

__global__ void k_hist_prep(const int* __restrict__ ei, int E, int* __restrict__ deg, int npr,
                            const float* __restrict__ x,
                            const float* __restrict__ W_in,
                            const float* __restrict__ W_self,
                            const float* __restrict__ W_nbr,
                            u16* __restrict__ xf,
                            u16* __restrict__ WtI_hi, u16* __restrict__ WtI_lo,
                            u16* __restrict__ WtS_hi, u16* __restrict__ WtS_lo,
                            u16* __restrict__ WtN_hi, u16* __restrict__ WtN_lo,
                            int L, int nxg) {
    // ---- histogram part ----
    {
        int r  = blockIdx.x & 7;
        int lo = r * npr, hi = lo + npr;
        int nb = gridDim.x >> 3;
        int bi = blockIdx.x >> 3;
        int tid = bi * blockDim.x + threadIdx.x;
        int stride = nb * blockDim.x;
        if ((E & 3) == 0) {
            const int4* d4 = (const int4*)(ei + E);
            int nch = E >> 2;
            for (int c = tid; c < nch; c += stride) {
                int4 d = d4[c];
                if (d.x >= lo && d.x < hi) atomicAdd(&deg[d.x], 1);
                if (d.y >= lo && d.y < hi) atomicAdd(&deg[d.y], 1);
                if (d.z >= lo && d.z < hi) atomicAdd(&deg[d.z], 1);
                if (d.w >= lo && d.w < hi) atomicAdd(&deg[d.w], 1);
            }
        } else {
            for (int e = tid; e < E; e += stride) {
                int d = ei[E + e];
                if (d >= lo && d < hi) atomicAdd(&deg[d], 1);
            }
        }
    }
    // ---- prep part: weights (transpose + fp32->bf16 hi/lo) and x frag-major repack ----
    {
        int nIn = 64 * 128;
        int nSq = L * 128 * 128;
        int wtot = nIn + 2 * nSq;
        int total = wtot + nxg;
        int stride = gridDim.x * blockDim.x;
        for (int i = blockIdx.x * blockDim.x + threadIdx.x; i < total; i += stride) {
            if (i >= wtot) {
                int t = i - wtot;
                int row = t >> 3, c = t & 7;
                const float4* xs = (const float4*)(x + (size_t)row * 64 + c * 8);
                float4 v0 = xs[0], v1 = xs[1];
                ushort8_t o;
                o[0] = f2bf(v0.x); o[1] = f2bf(v0.y); o[2] = f2bf(v0.z); o[3] = f2bf(v0.w);
                o[4] = f2bf(v1.x); o[5] = f2bf(v1.y); o[6] = f2bf(v1.z); o[7] = f2bf(v1.w);
                int T = row >> 4, m = row & 15;
                int f = c >> 2, q = c & 3;
                *(ushort8_t*)&xf[((size_t)(T * 2 + f) * 64 + q * 16 + m) * 8] = o;
            } else {
                float v; u16* phi; u16* plo; int o;
                if (i < nIn) {
                    int n = i / 64, k = i % 64;
                    v = W_in[k * 128 + n]; phi = WtI_hi; plo = WtI_lo; o = n * 64 + k;
                } else if (i < nIn + nSq) {
                    int t = i - nIn;
                    int l = t / (128 * 128), r = t % (128 * 128);
                    int n = r / 128, k = r % 128;
                    v = W_self[l * 128 * 128 + k * 128 + n]; phi = WtS_hi; plo = WtS_lo;
                    o = l * 128 * 128 + n * 128 + k;
                } else {
                    int t = i - nIn - nSq;
                    int l = t / (128 * 128), r = t % (128 * 128);
                    int n = r / 128, k = r % 128;
                    v = W_nbr[l * 128 * 128 + k * 128 + n]; phi = WtN_hi; plo = WtN_lo;
                    o = l * 128 * 128 + n * 128 + k;
                }
                u16 hi = f2bf(v);
                phi[o] = hi;
                plo[o] = f2bf(v - bf2f(hi));
            }
        }
    }
}

__global__ void k_scan1(const int* __restrict__ deg, int* __restrict__ rowp,
                        int* __restrict__ bsums, int n) {
    __shared__ int sh[1024];
    int t = threadIdx.x;
    int base = blockIdx.x * 1024;
    int v = (base + t < n) ? deg[base + t] : 0;
    sh[t] = v;
    __syncthreads();
    for (int off = 1; off < 1024; off <<= 1) {
        int x = sh[t];
        int y = (t >= off) ? sh[t - off] : 0;
        __syncthreads();
        sh[t] = x + y;
        __syncthreads();
    }
    if (base + t < n) rowp[base + t + 1] = sh[t];
    if (t == 1023) bsums[blockIdx.x] = sh[1023];
}

// merged scan2+scan3: each block locally re-scans bsums in LDS, applies offset, writes fillp.
__global__ void k_scan_tail(int* __restrict__ rowp, const int* __restrict__ bsums,
                            int* __restrict__ fillp, int n, int nb) {
    __shared__ int sh[1024];
    int t = threadIdx.x;
    int b = blockIdx.x;
    sh[t] = (t < nb) ? bsums[t] : 0;
    __syncthreads();
    for (int off = 1; off < 1024; off <<= 1) {
        int x = sh[t];
        int y = (t >= off) ? sh[t - off] : 0;
        __syncthreads();
        sh[t] = x + y;
        __syncthreads();
    }
    int boff = (b == 0) ? 0 : sh[b - 1];
    int base = b * 1024;
    if (base + t < n) {
        int v = rowp[base + t + 1] + boff;
        rowp[base + t + 1] = v;
        if (base + t + 1 < n) fillp[base + t + 1] = v;
    }
    if (b == 0 && t == 0) { rowp[0] = 0; fillp[0] = 0; }
}

// ---------------- device fn: CSR fill (XCD-range-partitioned scatter) ----------------

__device__ __forceinline__ void dev_fill(const int* __restrict__ ei, int E,
                                         int* __restrict__ fillpos, int* __restrict__ colx,
                                         int npr, int bid, int nbF) {
    int r  = bid & 7;
    int lo = r * npr, hi = lo + npr;
    int nb = nbF >> 3;
    int bi = bid >> 3;
    int tid = bi * blockDim.x + threadIdx.x;
    int stride = nb * blockDim.x;
    if ((E & 3) == 0) {
        const int4* s4 = (const int4*)ei;
        const int4* d4 = (const int4*)(ei + E);
        int nch = E >> 2;
        for (int c = tid; c < nch; c += stride) {
            int4 d = d4[c];
            bool m0 = d.x >= lo && d.x < hi;
            bool m1 = d.y >= lo && d.y < hi;
            bool m2 = d.z >= lo && d.z < hi;
            bool m3 = d.w >= lo && d.w < hi;
            if (m0 | m1 | m2 | m3) {
                int4 s = s4[c];
                if (m0) colx[atomicAdd(&fillpos[d.x], 1)] = s.x;
                if (m1) colx[atomicAdd(&fillpos[d.y], 1)] = s.y;
                if (m2) colx[atomicAdd(&fillpos[d.z], 1)] = s.z;
                if (m3) colx[atomicAdd(&fillpos[d.w], 1)] = s.w;
            }
        }
    } else {
        for (int e = tid; e < E; e += stride) {
            int d = ei[E + e];
            if (d >= lo && d < hi) colx[atomicAdd(&fillpos[d], 1)] = ei[e];
        }
    }
}

// ---------------- aggregation: Sf = bf16(mean over CSR row of hb rows), fragment-major out ----
// 16 lanes/node, 16B (ushort8) gathers, 16 outstanding loads (order == two consecutive
// 8-chunks -> bit-identical numerics vs the 8-deep loop).

__global__ __launch_bounds__(256, 4) void k_agg(
        const ushort8_t* __restrict__ hb8, const int* __restrict__ rowp,
        const int* __restrict__ colx, u16* __restrict__ Sf, int n) {
    int g = (blockIdx.x * blockDim.x + threadIdx.x) >> 4;   // 16 lanes/node, lane = 8 cols
    int lane = threadIdx.x & 15;
    if (g >= n) return;
    int beg = rowp[g];
    int end = rowp[g + 1];
    float a0[8], a1[8];
#pragma unroll
    for (int j = 0; j < 8; ++j) { a0[j] = 0.f; a1[j] = 0.f; }
    int e = beg;
    for (; e + 15 < end; e += 16) {
        int s0 = colx[e],      s1 = colx[e + 1],  s2 = colx[e + 2],  s3 = colx[e + 3];
        int s4 = colx[e + 4],  s5 = colx[e + 5],  s6 = colx[e + 6],  s7 = colx[e + 7];
        int s8 = colx[e + 8],  s9 = colx[e + 9],  sa = colx[e + 10], sb = colx[e + 11];
        int sc = colx[e + 12], sd = colx[e + 13], se = colx[e + 14], sf = colx[e + 15];
        ushort8_t v0 = hb8[(size_t)s0 * 16 + lane];
        ushort8_t v1 = hb8[(size_t)s1 * 16 + lane];
        ushort8_t v2 = hb8[(size_t)s2 * 16 + lane];
        ushort8_t v3 = hb8[(size_t)s3 * 16 + lane];
        ushort8_t v4 = hb8[(size_t)s4 * 16 + lane];
        ushort8_t v5 = hb8[(size_t)s5 * 16 + lane];
        ushort8_t v6 = hb8[(size_t)s6 * 16 + lane];
        ushort8_t v7 = hb8[(size_t)s7 * 16 + lane];
        ushort8_t v8 = hb8[(size_t)s8 * 16 + lane];
        ushort8_t v9 = hb8[(size_t)s9 * 16 + lane];
        ushort8_t va = hb8[(size_t)sa * 16 + lane];
        ushort8_t vb = hb8[(size_t)sb * 16 + lane];
        ushort8_t vc = hb8[(size_t)sc * 16 + lane];
        ushort8_t vd = hb8[(size_t)sd * 16 + lane];
        ushort8_t ve = hb8[(size_t)se * 16 + lane];
        ushort8_t vf = hb8[(size_t)sf * 16 + lane];
#pragma unroll
        for (int j = 0; j < 8; ++j) {
            a0[j] += bf2f(v0[j]); a1[j] += bf2f(v1[j]);
            a0[j] += bf2f(v2[j]); a1[j] += bf2f(v3[j]);
            a0[j] += bf2f(v4[j]); a1[j] += bf2f(v5[j]);
            a0[j] += bf2f(v6[j]); a1[j] += bf2f(v7[j]);
        }
#pragma unroll
        for (int j = 0; j < 8; ++j) {
            a0[j] += bf2f(v8[j]); a1[j] += bf2f(v9[j]);
            a0[j] += bf2f(va[j]); a1[j] += bf2f(vb[j]);
            a0[j] += bf2f(vc[j]); a1[j] += bf2f(vd[j]);
            a0[j] += bf2f(ve[j]); a1[j] += bf2f(vf[j]);
        }
    }
    for (; e + 7 < end; e += 8) {
        int s0 = colx[e],     s1 = colx[e + 1], s2 = colx[e + 2], s3 = colx[e + 3];
        int s4 = colx[e + 4], s5 = colx[e + 5], s6 = colx[e + 6], s7 = colx[e + 7];
        ushort8_t v0 = hb8[(size_t)s0 * 16 + lane];
        ushort8_t v1 = hb8[(size_t)s1 * 16 + lane];
        ushort8_t v2 = hb8[(size_t)s2 * 16 + lane];
        ushort8_t v3 = hb8[(size_t)s3 * 16 + lane];
        ushort8_t v4 = hb8[(size_t)s4 * 16 + lane];
        ushort8_t v5 = hb8[(size_t)s5 * 16 + lane];
        ushort8_t v6 = hb8[(size_t)s6 * 16 + lane];
        ushort8_t v7 = hb8[(size_t)s7 * 16 + lane];
#pragma unroll
        for (int j = 0; j < 8; ++j) {
            a0[j] += bf2f(v0[j]); a1[j] += bf2f(v1[j]);
            a0[j] += bf2f(v2[j]); a1[j] += bf2f(v3[j]);
            a0[j] += bf2f(v4[j]); a1[j] += bf2f(v5[j]);
            a0[j] += bf2f(v6[j]); a1[j] += bf2f(v7[j]);
        }
    }
    for (; e + 3 < end; e += 4) {
        int s0 = colx[e], s1 = colx[e + 1], s2 = colx[e + 2], s3 = colx[e + 3];
        ushort8_t v0 = hb8[(size_t)s0 * 16 + lane];
        ushort8_t v1 = hb8[(size_t)s1 * 16 + lane];
        ushort8_t v2 = hb8[(size_t)s2 * 16 + lane];
        ushort8_t v3 = hb8[(size_t)s3 * 16 + lane];
#pragma unroll
        for (int j = 0; j < 8; ++j) {
            a0[j] += bf2f(v0[j]); a1[j] += bf2f(v1[j]);
            a0[j] += bf2f(v2[j]); a1[j] += bf2f(v3[j]);
        }
    }
    for (; e < end; ++e) {
        int s = colx[e];
        ushort8_t v = hb8[(size_t)s * 16 + lane];
#pragma unroll
        for (int j = 0; j < 8; ++j) a0[j] += bf2f(v[j]);
    }
    int deg = end - beg;
    float inv = 1.0f / (float)(deg > 1 ? deg : 1);
    ushort8_t o;
#pragma unroll
    for (int j = 0; j < 8; ++j) o[j] = f2bf((a0[j] + a1[j]) * inv);
    // fragment-major store (KF=4): lane's cols lane*8..lane*8+7 = one contiguous j-group
    int T = g >> 4, m = g & 15;
    *(ushort8_t*)&Sf[((size_t)(T * 4 + (lane >> 2)) * 64 + (lane & 3) * 16 + m) * 8] = o;
}

// ---------------- device fn: MFMA GEMM (frag-major A, register-persistent B, prefetch) ----
// body identical to round-3 k_gemm_mfma; bid/gdim passed explicitly for fused dispatch.

template <int KF1, int KF2, int DO_ELU>
__device__ __forceinline__ void dev_gemm(
    const u16* __restrict__ A1f, const u16* __restrict__ A2f,
    const u16* __restrict__ B1h, const u16* __restrict__ B1l,
    const u16* __restrict__ B2h, const u16* __restrict__ B2l,
    const float* __restrict__ bias, float* __restrict__ C,
    u16* __restrict__ Hrow, u16* __restrict__ Hf,
    int M, int bid, int gdim)
{
    constexpr int K1 = KF1 * 32;
    constexpr int K2 = KF2 * 32;
    constexpr int KF = KF1 + KF2;
    int lane = threadIdx.x & 63;
    int w    = threadIdx.x >> 6;
    int m16  = lane & 15;
    int quad = lane >> 4;
    int kq   = quad * 8;
    int ng   = (bid >> 3) & 1;
    int mtb  = (bid & 7) | ((bid >> 4) << 3);   // [0, gdim/2)
    int ncol = (ng * 4 + w) * 16 + m16;

    frag_t bh[KF], bl[KF];
    if constexpr (KF1 > 0) {
#pragma unroll
        for (int f = 0; f < KF1; ++f) {
            bh[f] = *(const frag_t*)&B1h[(size_t)ncol * K1 + f * 32 + kq];
            bl[f] = *(const frag_t*)&B1l[(size_t)ncol * K1 + f * 32 + kq];
        }
    }
    if constexpr (KF2 > 0) {
#pragma unroll
        for (int f = 0; f < KF2; ++f) {
            bh[KF1 + f] = *(const frag_t*)&B2h[(size_t)ncol * K2 + f * 32 + kq];
            bl[KF1 + f] = *(const frag_t*)&B2l[(size_t)ncol * K2 + f * 32 + kq];
        }
    }

    float bv = bias[ncol];
    int nMT  = (M + 31) >> 5;
    int step = gdim >> 1;
    int fcol = ncol >> 5;
    int qcol = (ncol & 31) >> 3;
    int jcol = ncol & 7;

    auto loadA = [&](int mt, frag_t (&a0)[KF], frag_t (&a1)[KF]) {
        int T0 = mt * 2, T1 = T0 + 1;   // padded alloc: no guards
        if constexpr (KF1 > 0) {
#pragma unroll
            for (int f = 0; f < KF1; ++f) {
                a0[f] = *(const frag_t*)&A1f[((size_t)(T0 * KF1 + f) * 64 + lane) * 8];
                a1[f] = *(const frag_t*)&A1f[((size_t)(T1 * KF1 + f) * 64 + lane) * 8];
            }
        }
        if constexpr (KF2 > 0) {
#pragma unroll
            for (int f = 0; f < KF2; ++f) {
                a0[KF1 + f] = *(const frag_t*)&A2f[((size_t)(T0 * KF2 + f) * 64 + lane) * 8];
                a1[KF1 + f] = *(const frag_t*)&A2f[((size_t)(T1 * KF2 + f) * 64 + lane) * 8];
            }
        }
    };

    auto compute = [&](int mt, frag_t (&a0)[KF], frag_t (&a1)[KF]) {
        f32x4_t acc0 = (f32x4_t){0.f, 0.f, 0.f, 0.f};
        f32x4_t acc1 = (f32x4_t){0.f, 0.f, 0.f, 0.f};
#pragma unroll
        for (int f = 0; f < KF; ++f) {
            acc0 = __builtin_amdgcn_mfma_f32_16x16x32_bf16(a0[f], bh[f], acc0, 0, 0, 0);
            acc1 = __builtin_amdgcn_mfma_f32_16x16x32_bf16(a1[f], bh[f], acc1, 0, 0, 0);
            acc0 = __builtin_amdgcn_mfma_f32_16x16x32_bf16(a0[f], bl[f], acc0, 0, 0, 0);
            acc1 = __builtin_amdgcn_mfma_f32_16x16x32_bf16(a1[f], bl[f], acc1, 0, 0, 0);
        }
        int rb = mt * 32 + quad * 4;
#pragma unroll
        for (int r = 0; r < 4; ++r) {
#pragma unroll
            for (int half = 0; half < 2; ++half) {
                int row = rb + r + half * 16;
                float av = half ? acc1[r] : acc0[r];
                if (row < M) {
                    float v = av + bv;
                    if constexpr (DO_ELU) v = (v > 0.f) ? v : expm1f(v);
                    if (C) C[(size_t)row * HIDDEN + ncol] = v;
                    if (Hrow) {
                        u16 hv = f2bf(v);
                        Hrow[(size_t)row * HIDDEN + ncol] = hv;
                        Hf[((size_t)((row >> 4) * 4 + fcol) * 64 + qcol * 16 + (row & 15)) * 8 + jcol] = hv;
                    }
                }
            }
        }
    };

    int mt = mtb;
    if (mt < nMT) {
        frag_t xa0[KF], xa1[KF], ya0[KF], ya1[KF];
        loadA(mt, xa0, xa1);
        while (true) {
            int mt2 = mt + step;
            if (mt2 < nMT) loadA(mt2, ya0, ya1);       // prefetch under compute(mt)
            compute(mt, xa0, xa1);
            if (mt2 >= nMT) break;
            int mt3 = mt2 + step;
            if (mt3 < nMT) loadA(mt3, xa0, xa1);       // prefetch under compute(mt2)
            compute(mt2, ya0, ya1);
            if (mt3 >= nMT) break;
            mt = mt3;
        }
    }
}

// layer GEMM wrapper (standalone dispatch)
template <int KF1, int KF2, int DO_ELU>
__global__ __launch_bounds__(256, 2) void k_gemm_mfma(
    const u16* __restrict__ A1f, const u16* __restrict__ A2f,
    const u16* __restrict__ B1h, const u16* __restrict__ B1l,
    const u16* __restrict__ B2h, const u16* __restrict__ B2l,
    const float* __restrict__ bias, float* __restrict__ C,
    u16* __restrict__ Hrow, u16* __restrict__ Hf, int M)
{
    dev_gemm<KF1, KF2, DO_ELU>(A1f, A2f, B1h, B1l, B2h, B2l, bias, C, Hrow, Hf,
                               M, blockIdx.x, gridDim.x);
}

// fused dispatch: CSR fill (blocks [0,nbF)) || input-projection GEMM (blocks [nbF, nbF+gdim)).
// Independent work: fill writes colx/fillp; gemm reads xf/WtI (from hist_prep), writes hRowA/hfA.
// Different pipes (atomic/memory vs MFMA) -> co-scheduled overlap; saves one boundary.

__global__ __launch_bounds__(256, 2) void k_fill_gemm(
    const int* __restrict__ ei, int E, int* __restrict__ fillpos, int* __restrict__ colx,
    int npr, int nbF,
    const u16* __restrict__ xf,
    const u16* __restrict__ WtI_hi, const u16* __restrict__ WtI_lo,
    const float* __restrict__ b_in,
    u16* __restrict__ hRow, u16* __restrict__ hf, int M, int gdim)
{
    if (blockIdx.x < (unsigned)nbF) {
        dev_fill(ei, E, fillpos, colx, npr, blockIdx.x, nbF);
    } else {
        dev_gemm<2, 0, 0>(xf, nullptr, WtI_hi, WtI_lo, nullptr, nullptr,
                          b_in, nullptr, hRow, hf, M, blockIdx.x - nbF, gdim);
    }
}

// ---------------- launch ----------------

extern "C" void kernel_launch(void* const* d_in, const int* in_sizes, int n_in,
                              void* d_out, int out_size, void* d_ws, size_t ws_size,
                              hipStream_t stream) {
    const float* x        = (const float*)d_in[0];
    const int* ei         = (const int*)d_in[1];
    const float* W_in     = (const float*)d_in[2];
    const float* b_in     = (const float*)d_in[3];
    const float* W_self   = (const float*)d_in[4];
    const float* b_self   = (const float*)d_in[5];
    const float* W_nbr    = (const float*)d_in[6];
    float* out = (float*)d_out;

    const int IN_FEAT = 64;
    int N = in_sizes[0] / IN_FEAT;           // 50000
    int E = in_sizes[1] / 2;                 // 800000
    int L = in_sizes[4] / (HIDDEN * HIDDEN); // 3

    char* ws = (char*)d_ws;
    size_t off = 0;
    auto alloc = [&](size_t bytes) -> void* {
        void* p = ws + off;
        off = (off + bytes + 255) & ~(size_t)255;
        return p;
    };

    int nT = ((N + 31) / 32) * 2;            // 16-row tiles, padded to macro-tile pairs

    u16* hRowA = (u16*)alloc((size_t)N * HIDDEN * 2);
    u16* hRowB = (u16*)alloc((size_t)N * HIDDEN * 2);
    u16* hfA   = (u16*)alloc((size_t)nT * 4 * 64 * 8 * 2);   // KF=4 frag-major
    u16* hfB   = (u16*)alloc((size_t)nT * 4 * 64 * 8 * 2);
    u16* xf    = (u16*)alloc((size_t)nT * 2 * 64 * 8 * 2);   // KF=2
    u16* Sf    = (u16*)alloc((size_t)nT * 4 * 64 * 8 * 2);
    u16* WtI_hi = (u16*)alloc(128 * 64 * 2);
    u16* WtI_lo = (u16*)alloc(128 * 64 * 2);
    u16* WtS_hi = (u16*)alloc((size_t)L * 128 * 128 * 2);
    u16* WtS_lo = (u16*)alloc((size_t)L * 128 * 128 * 2);
    u16* WtN_hi = (u16*)alloc((size_t)L * 128 * 128 * 2);
    u16* WtN_lo = (u16*)alloc((size_t)L * 128 * 128 * 2);
    int* deg   = (int*)alloc((size_t)N * sizeof(int));
    int* rowp  = (int*)alloc((size_t)(N + 1) * sizeof(int));
    int* fillp = (int*)alloc((size_t)N * sizeof(int));
    int* colx  = (int*)alloc((size_t)E * sizeof(int));
    int* bsums = (int*)alloc(1024 * sizeof(int));

    int npr = (N + 7) / 8;   // nodes per XCD range

    // CSR build (XCD-range-partitioned scatters) with prep fused into hist
    hipMemsetAsync(deg, 0, (size_t)N * sizeof(int), stream);
    int wtot = 64 * 128 + 2 * L * 128 * 128;
    (void)wtot;
    k_hist_prep<<<2048, 256, 0, stream>>>(ei, E, deg, npr,
                                          x, W_in, W_self, W_nbr, xf,
                                          WtI_hi, WtI_lo, WtS_hi, WtS_lo,
                                          WtN_hi, WtN_lo, L, N * 8);
    int nb = (N + 1023) / 1024;
    k_scan1<<<nb, 1024, 0, stream>>>(deg, rowp, bsums, N);
    k_scan_tail<<<nb, 1024, 0, stream>>>(rowp, bsums, fillp, N, nb);

    const int GB = 1024;   // gemm sub-grid: multiple of 16; ~3 tiles/block for prefetch
    const int NBF = 2048;  // fill sub-grid

    // fused: CSR fill || input projection h = bf16(x @ W_in + b_in) -> hRowA + hfA
    k_fill_gemm<<<NBF + GB, 256, 0, stream>>>(
        ei, E, fillp, colx, npr, NBF,
        xf, WtI_hi, WtI_lo, b_in, hRowA, hfA, N, GB);

    u16* curRow = hRowA; u16* curF = hfA;
    u16* nxtRow = hRowB; u16* nxtF = hfB;

    for (int l = 0; l < L; ++l) {
        k_agg<<<(N + 15) / 16, 256, 0, stream>>>((const ushort8_t*)curRow, rowp, colx, Sf, N);
        const u16* Wsh = WtS_hi + (size_t)l * 128 * 128;
        const u16* Wsl = WtS_lo + (size_t)l * 128 * 128;
        const u16* Wnh = WtN_hi + (size_t)l * 128 * 128;
        const u16* Wnl = WtN_lo + (size_t)l * 128 * 128;
        const float* bs = b_self + (size_t)l * HIDDEN;
        bool last = (l == L - 1);
        k_gemm_mfma<4, 4, 1><<<GB, 256, 0, stream>>>(
            curF, Sf,
            Wsh, Wsl, Wnh, Wnl,
            bs, last ? out : nullptr,
            last ? nullptr : nxtRow, last ? nullptr : nxtF, N);
        u16* tr = curRow; curRow = nxtRow; nxtRow = tr;
        u16* tf = curF;   curF = nxtF;     nxtF = tf;
    }
}

// Round 8
// 310.298 us; speedup vs baseline: 2.6287x; 1.0528x over previous
//
#include <hip/hip_runtime.h>
#include <cstdint>

#define HIDDEN 128
#define NC 32          // edge chunks per XCD range (counting-sort granularity)
#define NR 8           // XCD ranges
#define MAXNPR 6400    // max nodes per range held in LDS (N<=51200)

typedef unsigned short u16;
using frag_t   = __attribute__((ext_vector_type(8))) short;   // 8 bf16 (4 VGPRs)
using f32x4_t  = __attribute__((ext_vector_type(4))) float;   // MFMA accumulator
using ushort8_t = __attribute__((ext_vector_type(8))) unsigned short;

__device__ __forceinline__ float bf2f(u16 u) {
    union { unsigned int i; float f; } c;
    c.i = ((unsigned int)u) << 16;
    return c.f;
}
__device__ __forceinline__ u16 f2bf(float f) {
    unsigned int u = __float_as_uint(f);
    unsigned int r = (u + 0x7fffu + ((u >> 16) & 1u)) >> 16;   // RNE
    return (u16)r;
}

// ---------------- CSR pass A: LDS-staged histogram (zero global atomics) + prep fused ----------------
// block b = (range r = b&7, chunk j = b>>3). LDS hist of in-range dsts, then coalesced
// plain stores to counts[j][node]. Prep (weights + x repack) grid-strided over same blocks.

__global__ __launch_bounds__(256) void k_hist2_prep(
    const int* __restrict__ ei, int E, int* __restrict__ counts, int npr, int n,
    const float* __restrict__ x,
    const float* __restrict__ W_in,
    const float* __restrict__ W_self,
    const float* __restrict__ W_nbr,
    u16* __restrict__ xf,
    u16* __restrict__ WtI_hi, u16* __restrict__ WtI_lo,
    u16* __restrict__ WtS_hi, u16* __restrict__ WtS_lo,
    u16* __restrict__ WtN_hi, u16* __restrict__ WtN_lo,
    int L, int nxg)
{
    __shared__ int lh[MAXNPR];
    int r = blockIdx.x & (NR - 1);
    int j = blockIdx.x >> 3;
    int lo = r * npr;
    int hi = lo + npr; if (hi > n) hi = n;
    int nr = hi - lo;
    for (int i = threadIdx.x; i < nr; i += 256) lh[i] = 0;
    __syncthreads();

    int nch4 = E >> 2;
    int c0 = (int)((long long)j * nch4 / NC);
    int c1 = (int)((long long)(j + 1) * nch4 / NC);
    const int4* d4 = (const int4*)(ei + E);
    for (int c = c0 + threadIdx.x; c < c1; c += 256) {
        int4 d = d4[c];
        if (d.x >= lo && d.x < hi) atomicAdd(&lh[d.x - lo], 1);
        if (d.y >= lo && d.y < hi) atomicAdd(&lh[d.y - lo], 1);
        if (d.z >= lo && d.z < hi) atomicAdd(&lh[d.z - lo], 1);
        if (d.w >= lo && d.w < hi) atomicAdd(&lh[d.w - lo], 1);
    }
    if (j == NC - 1 && (E & 3)) {
        for (int e = (nch4 << 2) + threadIdx.x; e < E; e += 256) {
            int d = ei[E + e];
            if (d >= lo && d < hi) atomicAdd(&lh[d - lo], 1);
        }
    }
    __syncthreads();
    for (int i = threadIdx.x; i < nr; i += 256)
        counts[(size_t)j * n + lo + i] = lh[i];

    // ---- prep part: weights (transpose + fp32->bf16 hi/lo) and x frag-major repack ----
    {
        int nIn = 64 * 128;
        int nSq = L * 128 * 128;
        int wtot = nIn + 2 * nSq;
        int total = wtot + nxg;
        int stride = gridDim.x * blockDim.x;
        for (int i = blockIdx.x * blockDim.x + threadIdx.x; i < total; i += stride) {
            if (i >= wtot) {
                int t = i - wtot;
                int row = t >> 3, c = t & 7;
                const float4* xs = (const float4*)(x + (size_t)row * 64 + c * 8);
                float4 v0 = xs[0], v1 = xs[1];
                ushort8_t o;
                o[0] = f2bf(v0.x); o[1] = f2bf(v0.y); o[2] = f2bf(v0.z); o[3] = f2bf(v0.w);
                o[4] = f2bf(v1.x); o[5] = f2bf(v1.y); o[6] = f2bf(v1.z); o[7] = f2bf(v1.w);
                int T = row >> 4, m = row & 15;
                int f = c >> 2, q = c & 3;
                *(ushort8_t*)&xf[((size_t)(T * 2 + f) * 64 + q * 16 + m) * 8] = o;
            } else {
                float v; u16* phi; u16* plo; int o;
                if (i < nIn) {
                    int nn = i / 64, k = i % 64;
                    v = W_in[k * 128 + nn]; phi = WtI_hi; plo = WtI_lo; o = nn * 64 + k;
                } else if (i < nIn + nSq) {
                    int t = i - nIn;
                    int l = t / (128 * 128), rr = t % (128 * 128);
                    int nn = rr / 128, k = rr % 128;
                    v = W_self[l * 128 * 128 + k * 128 + nn]; phi = WtS_hi; plo = WtS_lo;
                    o = l * 128 * 128 + nn * 128 + k;
                } else {
                    int t = i - nIn - nSq;
                    int l = t / (128 * 128), rr = t % (128 * 128);
                    int nn = rr / 128, k = rr % 128;
                    v = W_nbr[l * 128 * 128 + k * 128 + nn]; phi = WtN_hi; plo = WtN_lo;
                    o = l * 128 * 128 + nn * 128 + k;
                }
                u16 hiv = f2bf(v);
                phi[o] = hiv;
                plo[o] = f2bf(v - bf2f(hiv));
            }
        }
    }
}

// ---------------- CSR pass B: per-node degree + exclusive prefix over chunks ----------------
// counts layout [j][node] -> per-j slices fully coalesced for loads and stores.

__global__ void k_deg(const int* __restrict__ counts, int* __restrict__ deg,
                      int* __restrict__ base, int n) {
    int v = blockIdx.x * blockDim.x + threadIdx.x;
    if (v >= n) return;
    int run = 0;
#pragma unroll
    for (int j = 0; j < NC; ++j) {
        int c = counts[(size_t)j * n + v];
        base[(size_t)j * n + v] = run;
        run += c;
    }
    deg[v] = run;
}

__global__ void k_scan1(const int* __restrict__ deg, int* __restrict__ rowp,
                        int* __restrict__ bsums, int n) {
    __shared__ int sh[1024];
    int t = threadIdx.x;
    int bb = blockIdx.x * 1024;
    int v = (bb + t < n) ? deg[bb + t] : 0;
    sh[t] = v;
    __syncthreads();
    for (int off = 1; off < 1024; off <<= 1) {
        int xx = sh[t];
        int y = (t >= off) ? sh[t - off] : 0;
        __syncthreads();
        sh[t] = xx + y;
        __syncthreads();
    }
    if (bb + t < n) rowp[bb + t + 1] = sh[t];
    if (t == 1023) bsums[blockIdx.x] = sh[1023];
}

// merged scan2+scan3: each block locally re-scans bsums in LDS, applies offset.
__global__ void k_scan_tail(int* __restrict__ rowp, const int* __restrict__ bsums,
                            int n, int nb) {
    __shared__ int sh[1024];
    int t = threadIdx.x;
    int b = blockIdx.x;
    sh[t] = (t < nb) ? bsums[t] : 0;
    __syncthreads();
    for (int off = 1; off < 1024; off <<= 1) {
        int xx = sh[t];
        int y = (t >= off) ? sh[t - off] : 0;
        __syncthreads();
        sh[t] = xx + y;
        __syncthreads();
    }
    int boff = (b == 0) ? 0 : sh[b - 1];
    int bb = b * 1024;
    if (bb + t < n) rowp[bb + t + 1] += boff;
    if (b == 0 && t == 0) rowp[0] = 0;
}

// ---------------- CSR pass C: fill via LDS cursors (zero global atomics) ----------------

__device__ __forceinline__ void dev_fill2(const int* __restrict__ ei, int E,
                                          const int* __restrict__ rowp,
                                          const int* __restrict__ base,
                                          int* __restrict__ colx,
                                          int npr, int n, int bid, int* lh) {
    int r = bid & (NR - 1);
    int j = bid >> 3;
    int lo = r * npr;
    int hi = lo + npr; if (hi > n) hi = n;
    int nr = hi - lo;
    for (int i = threadIdx.x; i < nr; i += 256) lh[i] = 0;
    __syncthreads();

    int nch4 = E >> 2;
    int c0 = (int)((long long)j * nch4 / NC);
    int c1 = (int)((long long)(j + 1) * nch4 / NC);
    const int4* s4 = (const int4*)ei;
    const int4* d4 = (const int4*)(ei + E);
    const int* basej = base + (size_t)j * n;
    for (int c = c0 + threadIdx.x; c < c1; c += 256) {
        int4 d = d4[c];
        bool m0 = d.x >= lo && d.x < hi;
        bool m1 = d.y >= lo && d.y < hi;
        bool m2 = d.z >= lo && d.z < hi;
        bool m3 = d.w >= lo && d.w < hi;
        if (m0 | m1 | m2 | m3) {
            int4 s = s4[c];
            if (m0) { int sl = atomicAdd(&lh[d.x - lo], 1); colx[rowp[d.x] + basej[d.x] + sl] = s.x; }
            if (m1) { int sl = atomicAdd(&lh[d.y - lo], 1); colx[rowp[d.y] + basej[d.y] + sl] = s.y; }
            if (m2) { int sl = atomicAdd(&lh[d.z - lo], 1); colx[rowp[d.z] + basej[d.z] + sl] = s.z; }
            if (m3) { int sl = atomicAdd(&lh[d.w - lo], 1); colx[rowp[d.w] + basej[d.w] + sl] = s.w; }
        }
    }
    if (j == NC - 1 && (E & 3)) {
        for (int e = (nch4 << 2) + threadIdx.x; e < E; e += 256) {
            int d = ei[E + e];
            if (d >= lo && d < hi) {
                int sl = atomicAdd(&lh[d - lo], 1);
                colx[rowp[d] + basej[d] + sl] = ei[e];
            }
        }
    }
}

// ---------------- aggregation: Sf = bf16(mean over CSR row of hb rows), fragment-major out ----
// 16 lanes/node, 16B (ushort8) gathers, 16 outstanding loads.

__global__ __launch_bounds__(256, 4) void k_agg(
        const ushort8_t* __restrict__ hb8, const int* __restrict__ rowp,
        const int* __restrict__ colx, u16* __restrict__ Sf, int n) {
    int g = (blockIdx.x * blockDim.x + threadIdx.x) >> 4;   // 16 lanes/node, lane = 8 cols
    int lane = threadIdx.x & 15;
    if (g >= n) return;
    int beg = rowp[g];
    int end = rowp[g + 1];
    float a0[8], a1[8];
#pragma unroll
    for (int j = 0; j < 8; ++j) { a0[j] = 0.f; a1[j] = 0.f; }
    int e = beg;
    for (; e + 15 < end; e += 16) {
        int s0 = colx[e],      s1 = colx[e + 1],  s2 = colx[e + 2],  s3 = colx[e + 3];
        int s4 = colx[e + 4],  s5 = colx[e + 5],  s6 = colx[e + 6],  s7 = colx[e + 7];
        int s8 = colx[e + 8],  s9 = colx[e + 9],  sa = colx[e + 10], sb = colx[e + 11];
        int sc = colx[e + 12], sd = colx[e + 13], se = colx[e + 14], sf = colx[e + 15];
        ushort8_t v0 = hb8[(size_t)s0 * 16 + lane];
        ushort8_t v1 = hb8[(size_t)s1 * 16 + lane];
        ushort8_t v2 = hb8[(size_t)s2 * 16 + lane];
        ushort8_t v3 = hb8[(size_t)s3 * 16 + lane];
        ushort8_t v4 = hb8[(size_t)s4 * 16 + lane];
        ushort8_t v5 = hb8[(size_t)s5 * 16 + lane];
        ushort8_t v6 = hb8[(size_t)s6 * 16 + lane];
        ushort8_t v7 = hb8[(size_t)s7 * 16 + lane];
        ushort8_t v8 = hb8[(size_t)s8 * 16 + lane];
        ushort8_t v9 = hb8[(size_t)s9 * 16 + lane];
        ushort8_t va = hb8[(size_t)sa * 16 + lane];
        ushort8_t vb = hb8[(size_t)sb * 16 + lane];
        ushort8_t vc = hb8[(size_t)sc * 16 + lane];
        ushort8_t vd = hb8[(size_t)sd * 16 + lane];
        ushort8_t ve = hb8[(size_t)se * 16 + lane];
        ushort8_t vf = hb8[(size_t)sf * 16 + lane];
#pragma unroll
        for (int j = 0; j < 8; ++j) {
            a0[j] += bf2f(v0[j]); a1[j] += bf2f(v1[j]);
            a0[j] += bf2f(v2[j]); a1[j] += bf2f(v3[j]);
            a0[j] += bf2f(v4[j]); a1[j] += bf2f(v5[j]);
            a0[j] += bf2f(v6[j]); a1[j] += bf2f(v7[j]);
        }
#pragma unroll
        for (int j = 0; j < 8; ++j) {
            a0[j] += bf2f(v8[j]); a1[j] += bf2f(v9[j]);
            a0[j] += bf2f(va[j]); a1[j] += bf2f(vb[j]);
            a0[j] += bf2f(vc[j]); a1[j] += bf2f(vd[j]);
            a0[j] += bf2f(ve[j]); a1[j] += bf2f(vf[j]);
        }
    }
    for (; e + 7 < end; e += 8) {
        int s0 = colx[e],     s1 = colx[e + 1], s2 = colx[e + 2], s3 = colx[e + 3];
        int s4 = colx[e + 4], s5 = colx[e + 5], s6 = colx[e + 6], s7 = colx[e + 7];
        ushort8_t v0 = hb8[(size_t)s0 * 16 + lane];
        ushort8_t v1 = hb8[(size_t)s1 * 16 + lane];
        ushort8_t v2 = hb8[(size_t)s2 * 16 + lane];
        ushort8_t v3 = hb8[(size_t)s3 * 16 + lane];
        ushort8_t v4 = hb8[(size_t)s4 * 16 + lane];
        ushort8_t v5 = hb8[(size_t)s5 * 16 + lane];
        ushort8_t v6 = hb8[(size_t)s6 * 16 + lane];
        ushort8_t v7 = hb8[(size_t)s7 * 16 + lane];
#pragma unroll
        for (int j = 0; j < 8; ++j) {
            a0[j] += bf2f(v0[j]); a1[j] += bf2f(v1[j]);
            a0[j] += bf2f(v2[j]); a1[j] += bf2f(v3[j]);
            a0[j] += bf2f(v4[j]); a1[j] += bf2f(v5[j]);
            a0[j] += bf2f(v6[j]); a1[j] += bf2f(v7[j]);
        }
    }
    for (; e + 3 < end; e += 4) {
        int s0 = colx[e], s1 = colx[e + 1], s2 = colx[e + 2], s3 = colx[e + 3];
        ushort8_t v0 = hb8[(size_t)s0 * 16 + lane];
        ushort8_t v1 = hb8[(size_t)s1 * 16 + lane];
        ushort8_t v2 = hb8[(size_t)s2 * 16 + lane];
        ushort8_t v3 = hb8[(size_t)s3 * 16 + lane];
#pragma unroll
        for (int j = 0; j < 8; ++j) {
            a0[j] += bf2f(v0[j]); a1[j] += bf2f(v1[j]);
            a0[j] += bf2f(v2[j]); a1[j] += bf2f(v3[j]);
        }
    }
    for (; e < end; ++e) {
        int s = colx[e];
        ushort8_t v = hb8[(size_t)s * 16 + lane];
#pragma unroll
        for (int j = 0; j < 8; ++j) a0[j] += bf2f(v[j]);
    }
    int deg = end - beg;
    float inv = 1.0f / (float)(deg > 1 ? deg : 1);
    ushort8_t o;
#pragma unroll
    for (int j = 0; j < 8; ++j) o[j] = f2bf((a0[j] + a1[j]) * inv);
    // fragment-major store (KF=4): lane's cols lane*8..lane*8+7 = one contiguous j-group
    int T = g >> 4, m = g & 15;
    *(ushort8_t*)&Sf[((size_t)(T * 4 + (lane >> 2)) * 64 + (lane & 3) * 16 + m) * 8] = o;
}

// ---------------- device fn: MFMA GEMM (frag-major A, register-persistent B, prefetch) ----

template <int KF1, int KF2, int DO_ELU>
__device__ __forceinline__ void dev_gemm(
    const u16* __restrict__ A1f, const u16* __restrict__ A2f,
    const u16* __restrict__ B1h, const u16* __restrict__ B1l,
    const u16* __restrict__ B2h, const u16* __restrict__ B2l,
    const float* __restrict__ bias, float* __restrict__ C,
    u16* __restrict__ Hrow, u16* __restrict__ Hf,
    int M, int bid, int gdim)
{
    constexpr int K1 = KF1 * 32;
    constexpr int K2 = KF2 * 32;
    constexpr int KF = KF1 + KF2;
    int lane = threadIdx.x & 63;
    int w    = threadIdx.x >> 6;
    int m16  = lane & 15;
    int quad = lane >> 4;
    int kq   = quad * 8;
    int ng   = (bid >> 3) & 1;
    int mtb  = (bid & 7) | ((bid >> 4) << 3);   // [0, gdim/2)
    int ncol = (ng * 4 + w) * 16 + m16;

    frag_t bh[KF], bl[KF];
    if constexpr (KF1 > 0) {
#pragma unroll
        for (int f = 0; f < KF1; ++f) {
            bh[f] = *(const frag_t*)&B1h[(size_t)ncol * K1 + f * 32 + kq];
            bl[f] = *(const frag_t*)&B1l[(size_t)ncol * K1 + f * 32 + kq];
        }
    }
    if constexpr (KF2 > 0) {
#pragma unroll
        for (int f = 0; f < KF2; ++f) {
            bh[KF1 + f] = *(const frag_t*)&B2h[(size_t)ncol * K2 + f * 32 + kq];
            bl[KF1 + f] = *(const frag_t*)&B2l[(size_t)ncol * K2 + f * 32 + kq];
        }
    }

    float bv = bias[ncol];
    int nMT  = (M + 31) >> 5;
    int step = gdim >> 1;
    int fcol = ncol >> 5;
    int qcol = (ncol & 31) >> 3;
    int jcol = ncol & 7;

    auto loadA = [&](int mt, frag_t (&a0)[KF], frag_t (&a1)[KF]) {
        int T0 = mt * 2, T1 = T0 + 1;   // padded alloc: no guards
        if constexpr (KF1 > 0) {
#pragma unroll
            for (int f = 0; f < KF1; ++f) {
                a0[f] = *(const frag_t*)&A1f[((size_t)(T0 * KF1 + f) * 64 + lane) * 8];
                a1[f] = *(const frag_t*)&A1f[((size_t)(T1 * KF1 + f) * 64 + lane) * 8];
            }
        }
        if constexpr (KF2 > 0) {
#pragma unroll
            for (int f = 0; f < KF2; ++f) {
                a0[KF1 + f] = *(const frag_t*)&A2f[((size_t)(T0 * KF2 + f) * 64 + lane) * 8];
                a1[KF1 + f] = *(const frag_t*)&A2f[((size_t)(T1 * KF2 + f) * 64 + lane) * 8];
            }
        }
    };

    auto compute = [&](int mt, frag_t (&a0)[KF], frag_t (&a1)[KF]) {
        f32x4_t acc0 = (f32x4_t){0.f, 0.f, 0.f, 0.f};
        f32x4_t acc1 = (f32x4_t){0.f, 0.f, 0.f, 0.f};
#pragma unroll
        for (int f = 0; f < KF; ++f) {
            acc0 = __builtin_amdgcn_mfma_f32_16x16x32_bf16(a0[f], bh[f], acc0, 0, 0, 0);
            acc1 = __builtin_amdgcn_mfma_f32_16x16x32_bf16(a1[f], bh[f], acc1, 0, 0, 0);
            acc0 = __builtin_amdgcn_mfma_f32_16x16x32_bf16(a0[f], bl[f], acc0, 0, 0, 0);
            acc1 = __builtin_amdgcn_mfma_f32_16x16x32_bf16(a1[f], bl[f], acc1, 0, 0, 0);
        }
        int rb = mt * 32 + quad * 4;
#pragma unroll
        for (int r = 0; r < 4; ++r) {
#pragma unroll
            for (int half = 0; half < 2; ++half) {
                int row = rb + r + half * 16;
                float av = half ? acc1[r] : acc0[r];
                if (row < M) {
                    float v = av + bv;
                    if constexpr (DO_ELU) v = (v > 0.f) ? v : expm1f(v);
                    if (C) C[(size_t)row * HIDDEN + ncol] = v;
                    if (Hrow) {
                        u16 hv = f2bf(v);
                        Hrow[(size_t)row * HIDDEN + ncol] = hv;
                        Hf[((size_t)((row >> 4) * 4 + fcol) * 64 + qcol * 16 + (row & 15)) * 8 + jcol] = hv;
                    }
                }
            }
        }
    };

    int mt = mtb;
    if (mt < nMT) {
        frag_t xa0[KF], xa1[KF], ya0[KF], ya1[KF];
        loadA(mt, xa0, xa1);
        while (true) {
            int mt2 = mt + step;
            if (mt2 < nMT) loadA(mt2, ya0, ya1);       // prefetch under compute(mt)
            compute(mt, xa0, xa1);
            if (mt2 >= nMT) break;
            int mt3 = mt2 + step;
            if (mt3 < nMT) loadA(mt3, xa0, xa1);       // prefetch under compute(mt2)
            compute(mt2, ya0, ya1);
            if (mt3 >= nMT) break;
            mt = mt3;
        }
    }
}

// layer GEMM wrapper (standalone dispatch)
template <int KF1, int KF2, int DO_ELU>
__global__ __launch_bounds__(256, 2) void k_gemm_mfma(
    const u16* __restrict__ A1f, const u16* __restrict__ A2f,
    const u16* __restrict__ B1h, const u16* __restrict__ B1l,
    const u16* __restrict__ B2h, const u16* __restrict__ B2l,
    const float* __restrict__ bias, float* __restrict__ C,
    u16* __restrict__ Hrow, u16* __restrict__ Hf, int M)
{
    dev_gemm<KF1, KF2, DO_ELU>(A1f, A2f, B1h, B1l, B2h, B2l, bias, C, Hrow, Hf,
                               M, blockIdx.x, gridDim.x);
}

// fused dispatch: LDS-cursor CSR fill (blocks [0,NBF)) || input-projection GEMM (rest).
// Independent: fill writes colx; gemm reads xf/WtI (from hist2_prep), writes hRowA/hfA.

__global__ __launch_bounds__(256, 2) void k_fill2_gemm(
    const int* __restrict__ ei, int E,
    const int* __restrict__ rowp, const int* __restrict__ base,
    int* __restrict__ colx, int npr, int n, int nbF,
    const u16* __restrict__ xf,
    const u16* __restrict__ WtI_hi, const u16* __restrict__ WtI_lo,
    const float* __restrict__ b_in,
    u16* __restrict__ hRow, u16* __restrict__ hf, int M, int gdim)
{
    __shared__ int cur[MAXNPR];
    if (blockIdx.x < (unsigned)nbF) {
        dev_fill2(ei, E, rowp, base, colx, npr, n, blockIdx.x, cur);
    } else {
        dev_gemm<2, 0, 0>(xf, nullptr, WtI_hi, WtI_lo, nullptr, nullptr,
                          b_in, nullptr, hRow, hf, M, blockIdx.x - nbF, gdim);
    }
}

// ---------------- launch ----------------

extern "C" void kernel_launch(void* const* d_in, const int* in_sizes, int n_in,
                              void* d_out, int out_size, void* d_ws, size_t ws_size,
                              hipStream_t stream) {
    const float* x        = (const float*)d_in[0];
    const int* ei         = (const int*)d_in[1];
    const float* W_in     = (const float*)d_in[2];
    const float* b_in     = (const float*)d_in[3];
    const float* W_self   = (const float*)d_in[4];
    const float* b_self   = (const float*)d_in[5];
    const float* W_nbr    = (const float*)d_in[6];
    float* out = (float*)d_out;

    const int IN_FEAT = 64;
    int N = in_sizes[0] / IN_FEAT;           // 50000
    int E = in_sizes[1] / 2;                 // 800000
    int L = in_sizes[4] / (HIDDEN * HIDDEN); // 3

    char* ws = (char*)d_ws;
    size_t off = 0;
    auto alloc = [&](size_t bytes) -> void* {
        void* p = ws + off;
        off = (off + bytes + 255) & ~(size_t)255;
        return p;
    };

    int nT = ((N + 31) / 32) * 2;            // 16-row tiles, padded to macro-tile pairs

    u16* hRowA = (u16*)alloc((size_t)N * HIDDEN * 2);
    u16* hRowB = (u16*)alloc((size_t)N * HIDDEN * 2);
    u16* hfA   = (u16*)alloc((size_t)nT * 4 * 64 * 8 * 2);   // KF=4 frag-major
    u16* hfB   = (u16*)alloc((size_t)nT * 4 * 64 * 8 * 2);
    u16* xf    = (u16*)alloc((size_t)nT * 2 * 64 * 8 * 2);   // KF=2
    u16* Sf    = (u16*)alloc((size_t)nT * 4 * 64 * 8 * 2);
    u16* WtI_hi = (u16*)alloc(128 * 64 * 2);
    u16* WtI_lo = (u16*)alloc(128 * 64 * 2);
    u16* WtS_hi = (u16*)alloc((size_t)L * 128 * 128 * 2);
    u16* WtS_lo = (u16*)alloc((size_t)L * 128 * 128 * 2);
    u16* WtN_hi = (u16*)alloc((size_t)L * 128 * 128 * 2);
    u16* WtN_lo = (u16*)alloc((size_t)L * 128 * 128 * 2);
    int* counts = (int*)alloc((size_t)NC * N * sizeof(int));
    int* base   = (int*)alloc((size_t)NC * N * sizeof(int));
    int* deg   = (int*)alloc((size_t)N * sizeof(int));
    int* rowp  = (int*)alloc((size_t)(N + 1) * sizeof(int));
    int* colx  = (int*)alloc((size_t)E * sizeof(int));
    int* bsums = (int*)alloc(1024 * sizeof(int));

    int npr = (N + NR - 1) / NR;   // nodes per XCD range (<= MAXNPR)

    // CSR pass A: LDS histogram (no global atomics, no memset) + prep fused
    k_hist2_prep<<<NR * NC, 256, 0, stream>>>(ei, E, counts, npr, N,
                                              x, W_in, W_self, W_nbr, xf,
                                              WtI_hi, WtI_lo, WtS_hi, WtS_lo,
                                              WtN_hi, WtN_lo, L, N * 8);
    // CSR pass B: degree + per-chunk exclusive prefix
    k_deg<<<(N + 255) / 256, 256, 0, stream>>>(counts, deg, base, N);
    int nb = (N + 1023) / 1024;
    k_scan1<<<nb, 1024, 0, stream>>>(deg, rowp, bsums, N);
    k_scan_tail<<<nb, 1024, 0, stream>>>(rowp, bsums, N, nb);

    const int GB = 1024;   // gemm sub-grid: multiple of 16; ~3 tiles/block for prefetch
    const int NBF = NR * NC;  // fill sub-grid (256)

    // fused: LDS-cursor CSR fill || input projection h = bf16(x @ W_in + b_in)
    k_fill2_gemm<<<NBF + GB, 256, 0, stream>>>(
        ei, E, rowp, base, colx, npr, N, NBF,
        xf, WtI_hi, WtI_lo, b_in, hRowA, hfA, N, GB);

    u16* curRow = hRowA; u16* curF = hfA;
    u16* nxtRow = hRowB; u16* nxtF = hfB;

    for (int l = 0; l < L; ++l) {
        k_agg<<<(N + 15) / 16, 256, 0, stream>>>((const ushort8_t*)curRow, rowp, colx, Sf, N);
        const u16* Wsh = WtS_hi + (size_t)l * 128 * 128;
        const u16* Wsl = WtS_lo + (size_t)l * 128 * 128;
        const u16* Wnh = WtN_hi + (size_t)l * 128 * 128;
        const u16* Wnl = WtN_lo + (size_t)l * 128 * 128;
        const float* bs = b_self + (size_t)l * HIDDEN;
        bool last = (l == L - 1);
        k_gemm_mfma<4, 4, 1><<<GB, 256, 0, stream>>>(
            curF, Sf,
            Wsh, Wsl, Wnh, Wnl,
            bs, last ? out : nullptr,
            last ? nullptr : nxtRow, last ? nullptr : nxtF, N);
        u16* tr = curRow; curRow = nxtRow; nxtRow = tr;
        u16* tf = curF;   curF = nxtF;     nxtF = tf;
    }
}

// Round 9
// 293.065 us; speedup vs baseline: 2.7833x; 1.0588x over previous
//
#include <hip/hip_runtime.h>
#include <cstdint>

#define HIDDEN 128
#define NC 128         // edge chunks per XCD range (counting-sort granularity / fill parallelism)
#define NR 8           // XCD ranges
#define MAXNPR 6400    // max nodes per range held in LDS (N<=51200)

typedef unsigned short u16;
using frag_t   = __attribute__((ext_vector_type(8))) short;   // 8 bf16 (4 VGPRs)
using f32x4_t  = __attribute__((ext_vector_type(4))) float;   // MFMA accumulator
using ushort8_t = __attribute__((ext_vector_type(8))) unsigned short;

__device__ __forceinline__ float bf2f(u16 u) {
    union { unsigned int i; float f; } c;
    c.i = ((unsigned int)u) << 16;
    return c.f;
}
__device__ __forceinline__ u16 f2bf(float f) {
    unsigned int u = __float_as_uint(f);
    unsigned int r = (u + 0x7fffu + ((u >> 16) & 1u)) >> 16;   // RNE
    return (u16)r;
}

// ---------------- CSR pass A: LDS-staged histogram (zero global atomics) + prep fused ----------------
// block b = (range r = b&7, chunk j = b>>3). LDS hist of in-range dsts, then coalesced
// plain stores to counts[j][node]. Prep (weights + x repack) grid-strided over same blocks.

__global__ __launch_bounds__(256) void k_hist2_prep(
    const int* __restrict__ ei, int E, int* __restrict__ counts, int npr, int n,
    const float* __restrict__ x,
    const float* __restrict__ W_in,
    const float* __restrict__ W_self,
    const float* __restrict__ W_nbr,
    u16* __restrict__ xf,
    u16* __restrict__ WtI_hi, u16* __restrict__ WtI_lo,
    u16* __restrict__ WtS_hi, u16* __restrict__ WtS_lo,
    u16* __restrict__ WtN_hi, u16* __restrict__ WtN_lo,
    int L, int nxg)
{
    __shared__ int lh[MAXNPR];
    int r = blockIdx.x & (NR - 1);
    int j = blockIdx.x >> 3;
    int lo = r * npr;
    int hi = lo + npr; if (hi > n) hi = n;
    int nr = hi - lo;
    for (int i = threadIdx.x; i < nr; i += 256) lh[i] = 0;
    __syncthreads();

    int nch4 = E >> 2;
    int c0 = (int)((long long)j * nch4 / NC);
    int c1 = (int)((long long)(j + 1) * nch4 / NC);
    const int4* d4 = (const int4*)(ei + E);
    for (int c = c0 + threadIdx.x; c < c1; c += 256) {
        int4 d = d4[c];
        if (d.x >= lo && d.x < hi) atomicAdd(&lh[d.x - lo], 1);
        if (d.y >= lo && d.y < hi) atomicAdd(&lh[d.y - lo], 1);
        if (d.z >= lo && d.z < hi) atomicAdd(&lh[d.z - lo], 1);
        if (d.w >= lo && d.w < hi) atomicAdd(&lh[d.w - lo], 1);
    }
    if (j == NC - 1 && (E & 3)) {
        for (int e = (nch4 << 2) + threadIdx.x; e < E; e += 256) {
            int d = ei[E + e];
            if (d >= lo && d < hi) atomicAdd(&lh[d - lo], 1);
        }
    }
    __syncthreads();
    for (int i = threadIdx.x; i < nr; i += 256)
        counts[(size_t)j * n + lo + i] = lh[i];

    // ---- prep part: weights (transpose + fp32->bf16 hi/lo) and x frag-major repack ----
    {
        int nIn = 64 * 128;
        int nSq = L * 128 * 128;
        int wtot = nIn + 2 * nSq;
        int total = wtot + nxg;
        int stride = gridDim.x * blockDim.x;
        for (int i = blockIdx.x * blockDim.x + threadIdx.x; i < total; i += stride) {
            if (i >= wtot) {
                int t = i - wtot;
                int row = t >> 3, c = t & 7;
                const float4* xs = (const float4*)(x + (size_t)row * 64 + c * 8);
                float4 v0 = xs[0], v1 = xs[1];
                ushort8_t o;
                o[0] = f2bf(v0.x); o[1] = f2bf(v0.y); o[2] = f2bf(v0.z); o[3] = f2bf(v0.w);
                o[4] = f2bf(v1.x); o[5] = f2bf(v1.y); o[6] = f2bf(v1.z); o[7] = f2bf(v1.w);
                int T = row >> 4, m = row & 15;
                int f = c >> 2, q = c & 3;
                *(ushort8_t*)&xf[((size_t)(T * 2 + f) * 64 + q * 16 + m) * 8] = o;
            } else {
                float v; u16* phi; u16* plo; int o;
                if (i < nIn) {
                    int nn = i / 64, k = i % 64;
                    v = W_in[k * 128 + nn]; phi = WtI_hi; plo = WtI_lo; o = nn * 64 + k;
                } else if (i < nIn + nSq) {
                    int t = i - nIn;
                    int l = t / (128 * 128), rr = t % (128 * 128);
                    int nn = rr / 128, k = rr % 128;
                    v = W_self[l * 128 * 128 + k * 128 + nn]; phi = WtS_hi; plo = WtS_lo;
                    o = l * 128 * 128 + nn * 128 + k;
                } else {
                    int t = i - nIn - nSq;
                    int l = t / (128 * 128), rr = t % (128 * 128);
                    int nn = rr / 128, k = rr % 128;
                    v = W_nbr[l * 128 * 128 + k * 128 + nn]; phi = WtN_hi; plo = WtN_lo;
                    o = l * 128 * 128 + nn * 128 + k;
                }
                u16 hiv = f2bf(v);
                phi[o] = hiv;
                plo[o] = f2bf(v - bf2f(hiv));
            }
        }
    }
}

// ---------------- CSR pass B: per-node degree + exclusive prefix over chunks ----------------
// counts layout [j][node] -> per-j slices fully coalesced for loads and stores.

__global__ void k_deg(const int* __restrict__ counts, int* __restrict__ deg,
                      int* __restrict__ base, int n) {
    int v = blockIdx.x * blockDim.x + threadIdx.x;
    if (v >= n) return;
    int run = 0;
#pragma unroll 8
    for (int j = 0; j < NC; ++j) {
        int c = counts[(size_t)j * n + v];
        base[(size_t)j * n + v] = run;
        run += c;
    }
    deg[v] = run;
}

__global__ void k_scan1(const int* __restrict__ deg, int* __restrict__ rowp,
                        int* __restrict__ bsums, int n) {
    __shared__ int sh[1024];
    int t = threadIdx.x;
    int bb = blockIdx.x * 1024;
    int v = (bb + t < n) ? deg[bb + t] : 0;
    sh[t] = v;
    __syncthreads();
    for (int off = 1; off < 1024; off <<= 1) {
        int xx = sh[t];
        int y = (t >= off) ? sh[t - off] : 0;
        __syncthreads();
        sh[t] = xx + y;
        __syncthreads();
    }
    if (bb + t < n) rowp[bb + t + 1] = sh[t];
    if (t == 1023) bsums[blockIdx.x] = sh[1023];
}

// merged scan2+scan3: each block locally re-scans bsums in LDS, applies offset.
__global__ void k_scan_tail(int* __restrict__ rowp, const int* __restrict__ bsums,
                            int n, int nb) {
    __shared__ int sh[1024];
    int t = threadIdx.x;
    int b = blockIdx.x;
    sh[t] = (t < nb) ? bsums[t] : 0;
    __syncthreads();
    for (int off = 1; off < 1024; off <<= 1) {
        int xx = sh[t];
        int y = (t >= off) ? sh[t - off] : 0;
        __syncthreads();
        sh[t] = xx + y;
        __syncthreads();
    }
    int boff = (b == 0) ? 0 : sh[b - 1];
    int bb = b * 1024;
    if (bb + t < n) rowp[bb + t + 1] += boff;
    if (b == 0 && t == 0) rowp[0] = 0;
}

// ---------------- CSR pass C: fill via LDS cursors (zero global atomics) ----------------

__device__ __forceinline__ void dev_fill2(const int* __restrict__ ei, int E,
                                          const int* __restrict__ rowp,
                                          const int* __restrict__ base,
                                          int* __restrict__ colx,
                                          int npr, int n, int bid, int* lh) {
    int r = bid & (NR - 1);
    int j = bid >> 3;
    int lo = r * npr;
    int hi = lo + npr; if (hi > n) hi = n;
    int nr = hi - lo;
    for (int i = threadIdx.x; i < nr; i += 256) lh[i] = 0;
    __syncthreads();

    int nch4 = E >> 2;
    int c0 = (int)((long long)j * nch4 / NC);
    int c1 = (int)((long long)(j + 1) * nch4 / NC);
    const int4* s4 = (const int4*)ei;
    const int4* d4 = (const int4*)(ei + E);
    const int* basej = base + (size_t)j * n;
    for (int c = c0 + threadIdx.x; c < c1; c += 256) {
        int4 d = d4[c];
        bool m0 = d.x >= lo && d.x < hi;
        bool m1 = d.y >= lo && d.y < hi;
        bool m2 = d.z >= lo && d.z < hi;
        bool m3 = d.w >= lo && d.w < hi;
        if (m0 | m1 | m2 | m3) {
            int4 s = s4[c];
            if (m0) { int sl = atomicAdd(&lh[d.x - lo], 1); colx[rowp[d.x] + basej[d.x] + sl] = s.x; }
            if (m1) { int sl = atomicAdd(&lh[d.y - lo], 1); colx[rowp[d.y] + basej[d.y] + sl] = s.y; }
            if (m2) { int sl = atomicAdd(&lh[d.z - lo], 1); colx[rowp[d.z] + basej[d.z] + sl] = s.z; }
            if (m3) { int sl = atomicAdd(&lh[d.w - lo], 1); colx[rowp[d.w] + basej[d.w] + sl] = s.w; }
        }
    }
    if (j == NC - 1 && (E & 3)) {
        for (int e = (nch4 << 2) + threadIdx.x; e < E; e += 256) {
            int d = ei[E + e];
            if (d >= lo && d < hi) {
                int sl = atomicAdd(&lh[d - lo], 1);
                colx[rowp[d] + basej[d] + sl] = ei[e];
            }
        }
    }
}

// ---------------- aggregation: Sf = bf16(mean over CSR row of hb rows), fragment-major out ----
// 16 lanes/node, 16B (ushort8) gathers, 16 outstanding loads.

__global__ __launch_bounds__(256, 4) void k_agg(
        const ushort8_t* __restrict__ hb8, const int* __restrict__ rowp,
        const int* __restrict__ colx, u16* __restrict__ Sf, int n) {
    int g = (blockIdx.x * blockDim.x + threadIdx.x) >> 4;   // 16 lanes/node, lane = 8 cols
    int lane = threadIdx.x & 15;
    if (g >= n) return;
    int beg = rowp[g];
    int end = rowp[g + 1];
    float a0[8], a1[8];
#pragma unroll
    for (int j = 0; j < 8; ++j) { a0[j] = 0.f; a1[j] = 0.f; }
    int e = beg;
    for (; e + 15 < end; e += 16) {
        int s0 = colx[e],      s1 = colx[e + 1],  s2 = colx[e + 2],  s3 = colx[e + 3];
        int s4 = colx[e + 4],  s5 = colx[e + 5],  s6 = colx[e + 6],  s7 = colx[e + 7];
        int s8 = colx[e + 8],  s9 = colx[e + 9],  sa = colx[e + 10], sb = colx[e + 11];
        int sc = colx[e + 12], sd = colx[e + 13], se = colx[e + 14], sf = colx[e + 15];
        ushort8_t v0 = hb8[(size_t)s0 * 16 + lane];
        ushort8_t v1 = hb8[(size_t)s1 * 16 + lane];
        ushort8_t v2 = hb8[(size_t)s2 * 16 + lane];
        ushort8_t v3 = hb8[(size_t)s3 * 16 + lane];
        ushort8_t v4 = hb8[(size_t)s4 * 16 + lane];
        ushort8_t v5 = hb8[(size_t)s5 * 16 + lane];
        ushort8_t v6 = hb8[(size_t)s6 * 16 + lane];
        ushort8_t v7 = hb8[(size_t)s7 * 16 + lane];
        ushort8_t v8 = hb8[(size_t)s8 * 16 + lane];
        ushort8_t v9 = hb8[(size_t)s9 * 16 + lane];
        ushort8_t va = hb8[(size_t)sa * 16 + lane];
        ushort8_t vb = hb8[(size_t)sb * 16 + lane];
        ushort8_t vc = hb8[(size_t)sc * 16 + lane];
        ushort8_t vd = hb8[(size_t)sd * 16 + lane];
        ushort8_t ve = hb8[(size_t)se * 16 + lane];
        ushort8_t vf = hb8[(size_t)sf * 16 + lane];
#pragma unroll
        for (int j = 0; j < 8; ++j) {
            a0[j] += bf2f(v0[j]); a1[j] += bf2f(v1[j]);
            a0[j] += bf2f(v2[j]); a1[j] += bf2f(v3[j]);
            a0[j] += bf2f(v4[j]); a1[j] += bf2f(v5[j]);
            a0[j] += bf2f(v6[j]); a1[j] += bf2f(v7[j]);
        }
#pragma unroll
        for (int j = 0; j < 8; ++j) {
            a0[j] += bf2f(v8[j]); a1[j] += bf2f(v9[j]);
            a0[j] += bf2f(va[j]); a1[j] += bf2f(vb[j]);
            a0[j] += bf2f(vc[j]); a1[j] += bf2f(vd[j]);
            a0[j] += bf2f(ve[j]); a1[j] += bf2f(vf[j]);
        }
    }
    for (; e + 7 < end; e += 8) {
        int s0 = colx[e],     s1 = colx[e + 1], s2 = colx[e + 2], s3 = colx[e + 3];
        int s4 = colx[e + 4], s5 = colx[e + 5], s6 = colx[e + 6], s7 = colx[e + 7];
        ushort8_t v0 = hb8[(size_t)s0 * 16 + lane];
        ushort8_t v1 = hb8[(size_t)s1 * 16 + lane];
        ushort8_t v2 = hb8[(size_t)s2 * 16 + lane];
        ushort8_t v3 = hb8[(size_t)s3 * 16 + lane];
        ushort8_t v4 = hb8[(size_t)s4 * 16 + lane];
        ushort8_t v5 = hb8[(size_t)s5 * 16 + lane];
        ushort8_t v6 = hb8[(size_t)s6 * 16 + lane];
        ushort8_t v7 = hb8[(size_t)s7 * 16 + lane];
#pragma unroll
        for (int j = 0; j < 8; ++j) {
            a0[j] += bf2f(v0[j]); a1[j] += bf2f(v1[j]);
            a0[j] += bf2f(v2[j]); a1[j] += bf2f(v3[j]);
            a0[j] += bf2f(v4[j]); a1[j] += bf2f(v5[j]);
            a0[j] += bf2f(v6[j]); a1[j] += bf2f(v7[j]);
        }
    }
    for (; e + 3 < end; e += 4) {
        int s0 = colx[e], s1 = colx[e + 1], s2 = colx[e + 2], s3 = colx[e + 3];
        ushort8_t v0 = hb8[(size_t)s0 * 16 + lane];
        ushort8_t v1 = hb8[(size_t)s1 * 16 + lane];
        ushort8_t v2 = hb8[(size_t)s2 * 16 + lane];
        ushort8_t v3 = hb8[(size_t)s3 * 16 + lane];
#pragma unroll
        for (int j = 0; j < 8; ++j) {
            a0[j] += bf2f(v0[j]); a1[j] += bf2f(v1[j]);
            a0[j] += bf2f(v2[j]); a1[j] += bf2f(v3[j]);
        }
    }
    for (; e < end; ++e) {
        int s = colx[e];
        ushort8_t v = hb8[(size_t)s * 16 + lane];
#pragma unroll
        for (int j = 0; j < 8; ++j) a0[j] += bf2f(v[j]);
    }
    int deg = end - beg;
    float inv = 1.0f / (float)(deg > 1 ? deg : 1);
    ushort8_t o;
#pragma unroll
    for (int j = 0; j < 8; ++j) o[j] = f2bf((a0[j] + a1[j]) * inv);
    // fragment-major store (KF=4): lane's cols lane*8..lane*8+7 = one contiguous j-group
    int T = g >> 4, m = g & 15;
    *(ushort8_t*)&Sf[((size_t)(T * 4 + (lane >> 2)) * 64 + (lane & 3) * 16 + m) * 8] = o;
}

// ---------------- device fn: MFMA GEMM (frag-major A, register-persistent B, prefetch) ----

template <int KF1, int KF2, int DO_ELU>
__device__ __forceinline__ void dev_gemm(
    const u16* __restrict__ A1f, const u16* __restrict__ A2f,
    const u16* __restrict__ B1h, const u16* __restrict__ B1l,
    const u16* __restrict__ B2h, const u16* __restrict__ B2l,
    const float* __restrict__ bias, float* __restrict__ C,
    u16* __restrict__ Hrow, u16* __restrict__ Hf,
    int M, int bid, int gdim)
{
    constexpr int K1 = KF1 * 32;
    constexpr int K2 = KF2 * 32;
    constexpr int KF = KF1 + KF2;
    int lane = threadIdx.x & 63;
    int w    = threadIdx.x >> 6;
    int m16  = lane & 15;
    int quad = lane >> 4;
    int kq   = quad * 8;
    int ng   = (bid >> 3) & 1;
    int mtb  = (bid & 7) | ((bid >> 4) << 3);   // [0, gdim/2)
    int ncol = (ng * 4 + w) * 16 + m16;

    frag_t bh[KF], bl[KF];
    if constexpr (KF1 > 0) {
#pragma unroll
        for (int f = 0; f < KF1; ++f) {
            bh[f] = *(const frag_t*)&B1h[(size_t)ncol * K1 + f * 32 + kq];
            bl[f] = *(const frag_t*)&B1l[(size_t)ncol * K1 + f * 32 + kq];
        }
    }
    if constexpr (KF2 > 0) {
#pragma unroll
        for (int f = 0; f < KF2; ++f) {
            bh[KF1 + f] = *(const frag_t*)&B2h[(size_t)ncol * K2 + f * 32 + kq];
            bl[KF1 + f] = *(const frag_t*)&B2l[(size_t)ncol * K2 + f * 32 + kq];
        }
    }

    float bv = bias[ncol];
    int nMT  = (M + 31) >> 5;
    int step = gdim >> 1;
    int fcol = ncol >> 5;
    int qcol = (ncol & 31) >> 3;
    int jcol = ncol & 7;

    auto loadA = [&](int mt, frag_t (&a0)[KF], frag_t (&a1)[KF]) {
        int T0 = mt * 2, T1 = T0 + 1;   // padded alloc: no guards
        if constexpr (KF1 > 0) {
#pragma unroll
            for (int f = 0; f < KF1; ++f) {
                a0[f] = *(const frag_t*)&A1f[((size_t)(T0 * KF1 + f) * 64 + lane) * 8];
                a1[f] = *(const frag_t*)&A1f[((size_t)(T1 * KF1 + f) * 64 + lane) * 8];
            }
        }
        if constexpr (KF2 > 0) {
#pragma unroll
            for (int f = 0; f < KF2; ++f) {
                a0[KF1 + f] = *(const frag_t*)&A2f[((size_t)(T0 * KF2 + f) * 64 + lane) * 8];
                a1[KF1 + f] = *(const frag_t*)&A2f[((size_t)(T1 * KF2 + f) * 64 + lane) * 8];
            }
        }
    };

    auto compute = [&](int mt, frag_t (&a0)[KF], frag_t (&a1)[KF]) {
        f32x4_t acc0 = (f32x4_t){0.f, 0.f, 0.f, 0.f};
        f32x4_t acc1 = (f32x4_t){0.f, 0.f, 0.f, 0.f};
#pragma unroll
        for (int f = 0; f < KF; ++f) {
            acc0 = __builtin_amdgcn_mfma_f32_16x16x32_bf16(a0[f], bh[f], acc0, 0, 0, 0);
            acc1 = __builtin_amdgcn_mfma_f32_16x16x32_bf16(a1[f], bh[f], acc1, 0, 0, 0);
            acc0 = __builtin_amdgcn_mfma_f32_16x16x32_bf16(a0[f], bl[f], acc0, 0, 0, 0);
            acc1 = __builtin_amdgcn_mfma_f32_16x16x32_bf16(a1[f], bl[f], acc1, 0, 0, 0);
        }
        int rb = mt * 32 + quad * 4;
#pragma unroll
        for (int r = 0; r < 4; ++r) {
#pragma unroll
            for (int half = 0; half < 2; ++half) {
                int row = rb + r + half * 16;
                float av = half ? acc1[r] : acc0[r];
                if (row < M) {
                    float v = av + bv;
                    if constexpr (DO_ELU) v = (v > 0.f) ? v : expm1f(v);
                    if (C) C[(size_t)row * HIDDEN + ncol] = v;
                    if (Hrow) {
                        u16 hv = f2bf(v);
                        Hrow[(size_t)row * HIDDEN + ncol] = hv;
                        Hf[((size_t)((row >> 4) * 4 + fcol) * 64 + qcol * 16 + (row & 15)) * 8 + jcol] = hv;
                    }
                }
            }
        }
    };

    int mt = mtb;
    if (mt < nMT) {
        frag_t xa0[KF], xa1[KF], ya0[KF], ya1[KF];
        loadA(mt, xa0, xa1);
        while (true) {
            int mt2 = mt + step;
            if (mt2 < nMT) loadA(mt2, ya0, ya1);       // prefetch under compute(mt)
            compute(mt, xa0, xa1);
            if (mt2 >= nMT) break;
            int mt3 = mt2 + step;
            if (mt3 < nMT) loadA(mt3, xa0, xa1);       // prefetch under compute(mt2)
            compute(mt2, ya0, ya1);
            if (mt3 >= nMT) break;
            mt = mt3;
        }
    }
}

// layer GEMM wrapper (standalone dispatch)
template <int KF1, int KF2, int DO_ELU>
__global__ __launch_bounds__(256, 2) void k_gemm_mfma(
    const u16* __restrict__ A1f, const u16* __restrict__ A2f,
    const u16* __restrict__ B1h, const u16* __restrict__ B1l,
    const u16* __restrict__ B2h, const u16* __restrict__ B2l,
    const float* __restrict__ bias, float* __restrict__ C,
    u16* __restrict__ Hrow, u16* __restrict__ Hf, int M)
{
    dev_gemm<KF1, KF2, DO_ELU>(A1f, A2f, B1h, B1l, B2h, B2l, bias, C, Hrow, Hf,
                               M, blockIdx.x, gridDim.x);
}

// fused dispatch: LDS-cursor CSR fill (blocks [0,NBF)) || input-projection GEMM (rest).
// Independent: fill writes colx; gemm reads xf/WtI (from hist2_prep), writes hRowA/hfA.

__global__ __launch_bounds__(256, 2) void k_fill2_gemm(
    const int* __restrict__ ei, int E,
    const int* __restrict__ rowp, const int* __restrict__ base,
    int* __restrict__ colx, int npr, int n, int nbF,
    const u16* __restrict__ xf,
    const u16* __restrict__ WtI_hi, const u16* __restrict__ WtI_lo,
    const float* __restrict__ b_in,
    u16* __restrict__ hRow, u16* __restrict__ hf, int M, int gdim)
{
    __shared__ int cur[MAXNPR];
    if (blockIdx.x < (unsigned)nbF) {
        dev_fill2(ei, E, rowp, base, colx, npr, n, blockIdx.x, cur);
    } else {
        dev_gemm<2, 0, 0>(xf, nullptr, WtI_hi, WtI_lo, nullptr, nullptr,
                          b_in, nullptr, hRow, hf, M, blockIdx.x - nbF, gdim);
    }
}

// ---------------- launch ----------------

extern "C" void kernel_launch(void* const* d_in, const int* in_sizes, int n_in,
                              void* d_out, int out_size, void* d_ws, size_t ws_size,
                              hipStream_t stream) {
    const float* x        = (const float*)d_in[0];
    const int* ei         = (const int*)d_in[1];
    const float* W_in     = (const float*)d_in[2];
    const float* b_in     = (const float*)d_in[3];
    const float* W_self   = (const float*)d_in[4];
    const float* b_self   = (const float*)d_in[5];
    const float* W_nbr    = (const float*)d_in[6];
    float* out = (float*)d_out;

    const int IN_FEAT = 64;
    int N = in_sizes[0] / IN_FEAT;           // 50000
    int E = in_sizes[1] / 2;                 // 800000
    int L = in_sizes[4] / (HIDDEN * HIDDEN); // 3

    char* ws = (char*)d_ws;
    size_t off = 0;
    auto alloc = [&](size_t bytes) -> void* {
        void* p = ws + off;
        off = (off + bytes + 255) & ~(size_t)255;
        return p;
    };

    int nT = ((N + 31) / 32) * 2;            // 16-row tiles, padded to macro-tile pairs

    u16* hRowA = (u16*)alloc((size_t)N * HIDDEN * 2);
    u16* hRowB = (u16*)alloc((size_t)N * HIDDEN * 2);
    u16* hfA   = (u16*)alloc((size_t)nT * 4 * 64 * 8 * 2);   // KF=4 frag-major
    u16* hfB   = (u16*)alloc((size_t)nT * 4 * 64 * 8 * 2);
    u16* xf    = (u16*)alloc((size_t)nT * 2 * 64 * 8 * 2);   // KF=2
    u16* Sf    = (u16*)alloc((size_t)nT * 4 * 64 * 8 * 2);
    u16* WtI_hi = (u16*)alloc(128 * 64 * 2);
    u16* WtI_lo = (u16*)alloc(128 * 64 * 2);
    u16* WtS_hi = (u16*)alloc((size_t)L * 128 * 128 * 2);
    u16* WtS_lo = (u16*)alloc((size_t)L * 128 * 128 * 2);
    u16* WtN_hi = (u16*)alloc((size_t)L * 128 * 128 * 2);
    u16* WtN_lo = (u16*)alloc((size_t)L * 128 * 128 * 2);
    int* counts = (int*)alloc((size_t)NC * N * sizeof(int));
    int* base   = (int*)alloc((size_t)NC * N * sizeof(int));
    int* deg   = (int*)alloc((size_t)N * sizeof(int));
    int* rowp  = (int*)alloc((size_t)(N + 1) * sizeof(int));
    int* colx  = (int*)alloc((size_t)E * sizeof(int));
    int* bsums = (int*)alloc(1024 * sizeof(int));

    int npr = (N + NR - 1) / NR;   // nodes per XCD range (<= MAXNPR)

    // CSR pass A: LDS histogram (no global atomics, no memset) + prep fused
    k_hist2_prep<<<NR * NC, 256, 0, stream>>>(ei, E, counts, npr, N,
                                              x, W_in, W_self, W_nbr, xf,
                                              WtI_hi, WtI_lo, WtS_hi, WtS_lo,
                                              WtN_hi, WtN_lo, L, N * 8);
    // CSR pass B: degree + per-chunk exclusive prefix
    k_deg<<<(N + 255) / 256, 256, 0, stream>>>(counts, deg, base, N);
    int nb = (N + 1023) / 1024;
    k_scan1<<<nb, 1024, 0, stream>>>(deg, rowp, bsums, N);
    k_scan_tail<<<nb, 1024, 0, stream>>>(rowp, bsums, N, nb);

    const int GB = 1024;   // gemm sub-grid: multiple of 16; ~3 tiles/block for prefetch
    const int NBF = NR * NC;  // fill sub-grid (1024)

    // fused: LDS-cursor CSR fill || input projection h = bf16(x @ W_in + b_in)
    k_fill2_gemm<<<NBF + GB, 256, 0, stream>>>(
        ei, E, rowp, base, colx, npr, N, NBF,
        xf, WtI_hi, WtI_lo, b_in, hRowA, hfA, N, GB);

    u16* curRow = hRowA; u16* curF = hfA;
    u16* nxtRow = hRowB; u16* nxtF = hfB;

    for (int l = 0; l < L; ++l) {
        k_agg<<<(N + 15) / 16, 256, 0, stream>>>((const ushort8_t*)curRow, rowp, colx, Sf, N);
        const u16* Wsh = WtS_hi + (size_t)l * 128 * 128;
        const u16* Wsl = WtS_lo + (size_t)l * 128 * 128;
        const u16* Wnh = WtN_hi + (size_t)l * 128 * 128;
        const u16* Wnl = WtN_lo + (size_t)l * 128 * 128;
        const float* bs = b_self + (size_t)l * HIDDEN;
        bool last = (l == L - 1);
        k_gemm_mfma<4, 4, 1><<<GB, 256, 0, stream>>>(
            curF, Sf,
            Wsh, Wsl, Wnh, Wnl,
            bs, last ? out : nullptr,
            last ? nullptr : nxtRow, last ? nullptr : nxtF, N);
        u16* tr = curRow; curRow = nxtRow; nxtRow = tr;
        u16* tf = curF;   curF = nxtF;     nxtF = tf;
    }
}

// Round 10
// 290.289 us; speedup vs baseline: 2.8099x; 1.0096x over previous
//
#include <hip/hip_runtime.h>
#include <cstdint>

#define HIDDEN 128
#define NC 128         // edge chunks per XCD range (counting-sort granularity / fill parallelism)
#define NR 8           // XCD ranges
#define MAXNPR 6400    // max nodes per range held in LDS (N<=51200)

typedef unsigned short u16;
using frag_t   = __attribute__((ext_vector_type(8))) short;   // 8 bf16 (4 VGPRs)
using f32x4_t  = __attribute__((ext_vector_type(4))) float;   // MFMA accumulator
using ushort8_t = __attribute__((ext_vector_type(8))) unsigned short;

__device__ __forceinline__ float bf2f(u16 u) {
    union { unsigned int i; float f; } c;
    c.i = ((unsigned int)u) << 16;
    return c.f;
}
__device__ __forceinline__ u16 f2bf(float f) {
    unsigned int u = __float_as_uint(f);
    unsigned int r = (u + 0x7fffu + ((u >> 16) & 1u)) >> 16;   // RNE
    return (u16)r;
}

// ---------------- CSR pass A: LDS-staged histogram (zero global atomics) + prep fused ----------------
// block b = (range r = b&7, chunk j = b>>3). LDS hist of in-range dsts, then coalesced
// plain u16 stores to counts[j][node]. Prep (weights + x repack) grid-strided over same blocks.

__global__ __launch_bounds__(256) void k_hist2_prep(
    const int* __restrict__ ei, int E, u16* __restrict__ counts, int npr, int n,
    const float* __restrict__ x,
    const float* __restrict__ W_in,
    const float* __restrict__ W_self,
    const float* __restrict__ W_nbr,
    u16* __restrict__ xf,
    u16* __restrict__ WtI_hi, u16* __restrict__ WtI_lo,
    u16* __restrict__ WtS_hi, u16* __restrict__ WtS_lo,
    u16* __restrict__ WtN_hi, u16* __restrict__ WtN_lo,
    int L, int nxg)
{
    __shared__ int lh[MAXNPR];
    int r = blockIdx.x & (NR - 1);
    int j = blockIdx.x >> 3;
    int lo = r * npr;
    int hi = lo + npr; if (hi > n) hi = n;
    int nr = hi - lo;
    for (int i = threadIdx.x; i < nr; i += 256) lh[i] = 0;
    __syncthreads();

    int nch4 = E >> 2;
    int c0 = (int)((long long)j * nch4 / NC);
    int c1 = (int)((long long)(j + 1) * nch4 / NC);
    const int4* d4 = (const int4*)(ei + E);
    for (int c = c0 + threadIdx.x; c < c1; c += 256) {
        int4 d = d4[c];
        if (d.x >= lo && d.x < hi) atomicAdd(&lh[d.x - lo], 1);
        if (d.y >= lo && d.y < hi) atomicAdd(&lh[d.y - lo], 1);
        if (d.z >= lo && d.z < hi) atomicAdd(&lh[d.z - lo], 1);
        if (d.w >= lo && d.w < hi) atomicAdd(&lh[d.w - lo], 1);
    }
    if (j == NC - 1 && (E & 3)) {
        for (int e = (nch4 << 2) + threadIdx.x; e < E; e += 256) {
            int d = ei[E + e];
            if (d >= lo && d < hi) atomicAdd(&lh[d - lo], 1);
        }
    }
    __syncthreads();
    for (int i = threadIdx.x; i < nr; i += 256)
        counts[(size_t)j * n + lo + i] = (u16)lh[i];

    // ---- prep part: weights (transpose + fp32->bf16 hi/lo) and x frag-major repack ----
    {
        int nIn = 64 * 128;
        int nSq = L * 128 * 128;
        int wtot = nIn + 2 * nSq;
        int total = wtot + nxg;
        int stride = gridDim.x * blockDim.x;
        for (int i = blockIdx.x * blockDim.x + threadIdx.x; i < total; i += stride) {
            if (i >= wtot) {
                int t = i - wtot;
                int row = t >> 3, c = t & 7;
                const float4* xs = (const float4*)(x + (size_t)row * 64 + c * 8);
                float4 v0 = xs[0], v1 = xs[1];
                ushort8_t o;
                o[0] = f2bf(v0.x); o[1] = f2bf(v0.y); o[2] = f2bf(v0.z); o[3] = f2bf(v0.w);
                o[4] = f2bf(v1.x); o[5] = f2bf(v1.y); o[6] = f2bf(v1.z); o[7] = f2bf(v1.w);
                int T = row >> 4, m = row & 15;
                int f = c >> 2, q = c & 3;
                *(ushort8_t*)&xf[((size_t)(T * 2 + f) * 64 + q * 16 + m) * 8] = o;
            } else {
                float v; u16* phi; u16* plo; int o;
                if (i < nIn) {
                    int nn = i / 64, k = i % 64;
                    v = W_in[k * 128 + nn]; phi = WtI_hi; plo = WtI_lo; o = nn * 64 + k;
                } else if (i < nIn + nSq) {
                    int t = i - nIn;
                    int l = t / (128 * 128), rr = t % (128 * 128);
                    int nn = rr / 128, k = rr % 128;
                    v = W_self[l * 128 * 128 + k * 128 + nn]; phi = WtS_hi; plo = WtS_lo;
                    o = l * 128 * 128 + nn * 128 + k;
                } else {
                    int t = i - nIn - nSq;
                    int l = t / (128 * 128), rr = t % (128 * 128);
                    int nn = rr / 128, k = rr % 128;
                    v = W_nbr[l * 128 * 128 + k * 128 + nn]; phi = WtN_hi; plo = WtN_lo;
                    o = l * 128 * 128 + nn * 128 + k;
                }
                u16 hiv = f2bf(v);
                phi[o] = hiv;
                plo[o] = f2bf(v - bf2f(hiv));
            }
        }
    }
}

// ---------------- CSR pass B: deg + per-chunk prefix + block scan (merged k_deg + k_scan1) ----------------
// thread v: deg = sum_j counts[j][v], base[j][v] = exclusive prefix (u16, max degree << 65536);
// then 1024-wide block scan of deg -> rowp partial + block sums.

__global__ void k_deg_scan(const u16* __restrict__ counts, u16* __restrict__ base,
                           int* __restrict__ rowp, int* __restrict__ bsums, int n) {
    __shared__ int sh[1024];
    int t = threadIdx.x;
    int v = blockIdx.x * 1024 + t;
    int run = 0;
    if (v < n) {
#pragma unroll 8
        for (int j = 0; j < NC; ++j) {
            int c = counts[(size_t)j * n + v];
            base[(size_t)j * n + v] = (u16)run;
            run += c;
        }
    }
    sh[t] = run;
    __syncthreads();
    for (int off = 1; off < 1024; off <<= 1) {
        int xx = sh[t];
        int y = (t >= off) ? sh[t - off] : 0;
        __syncthreads();
        sh[t] = xx + y;
        __syncthreads();
    }
    if (v < n) rowp[v + 1] = sh[t];
    if (t == 1023) bsums[blockIdx.x] = sh[1023];
}

// merged scan2+scan3: each block locally re-scans bsums in LDS, applies offset.
__global__ void k_scan_tail(int* __restrict__ rowp, const int* __restrict__ bsums,
                            int n, int nb) {
    __shared__ int sh[1024];
    int t = threadIdx.x;
    int b = blockIdx.x;
    sh[t] = (t < nb) ? bsums[t] : 0;
    __syncthreads();
    for (int off = 1; off < 1024; off <<= 1) {
        int xx = sh[t];
        int y = (t >= off) ? sh[t - off] : 0;
        __syncthreads();
        sh[t] = xx + y;
        __syncthreads();
    }
    int boff = (b == 0) ? 0 : sh[b - 1];
    int bb = b * 1024;
    if (bb + t < n) rowp[bb + t + 1] += boff;
    if (b == 0 && t == 0) rowp[0] = 0;
}

// ---------------- CSR pass C: fill via LDS cursors (zero global atomics) ----------------

__device__ __forceinline__ void dev_fill2(const int* __restrict__ ei, int E,
                                          const int* __restrict__ rowp,
                                          const u16* __restrict__ base,
                                          int* __restrict__ colx,
                                          int npr, int n, int bid, int* lh) {
    int r = bid & (NR - 1);
    int j = bid >> 3;
    int lo = r * npr;
    int hi = lo + npr; if (hi > n) hi = n;
    int nr = hi - lo;
    for (int i = threadIdx.x; i < nr; i += 256) lh[i] = 0;
    __syncthreads();

    int nch4 = E >> 2;
    int c0 = (int)((long long)j * nch4 / NC);
    int c1 = (int)((long long)(j + 1) * nch4 / NC);
    const int4* s4 = (const int4*)ei;
    const int4* d4 = (const int4*)(ei + E);
    const u16* basej = base + (size_t)j * n;
    for (int c = c0 + threadIdx.x; c < c1; c += 256) {
        int4 d = d4[c];
        bool m0 = d.x >= lo && d.x < hi;
        bool m1 = d.y >= lo && d.y < hi;
        bool m2 = d.z >= lo && d.z < hi;
        bool m3 = d.w >= lo && d.w < hi;
        if (m0 | m1 | m2 | m3) {
            int4 s = s4[c];
            if (m0) { int sl = atomicAdd(&lh[d.x - lo], 1); colx[rowp[d.x] + (int)basej[d.x] + sl] = s.x; }
            if (m1) { int sl = atomicAdd(&lh[d.y - lo], 1); colx[rowp[d.y] + (int)basej[d.y] + sl] = s.y; }
            if (m2) { int sl = atomicAdd(&lh[d.z - lo], 1); colx[rowp[d.z] + (int)basej[d.z] + sl] = s.z; }
            if (m3) { int sl = atomicAdd(&lh[d.w - lo], 1); colx[rowp[d.w] + (int)basej[d.w] + sl] = s.w; }
        }
    }
    if (j == NC - 1 && (E & 3)) {
        for (int e = (nch4 << 2) + threadIdx.x; e < E; e += 256) {
            int d = ei[E + e];
            if (d >= lo && d < hi) {
                int sl = atomicAdd(&lh[d - lo], 1);
                colx[rowp[d] + (int)basej[d] + sl] = ei[e];
            }
        }
    }
}

// ---------------- aggregation: Sf = bf16(mean over CSR row of hb rows), fragment-major out ----
// 16 lanes/node, 16B (ushort8) gathers, 16 outstanding loads.

__global__ __launch_bounds__(256, 4) void k_agg(
        const ushort8_t* __restrict__ hb8, const int* __restrict__ rowp,
        const int* __restrict__ colx, u16* __restrict__ Sf, int n) {
    int g = (blockIdx.x * blockDim.x + threadIdx.x) >> 4;   // 16 lanes/node, lane = 8 cols
    int lane = threadIdx.x & 15;
    if (g >= n) return;
    int beg = rowp[g];
    int end = rowp[g + 1];
    float a0[8], a1[8];
#pragma unroll
    for (int j = 0; j < 8; ++j) { a0[j] = 0.f; a1[j] = 0.f; }
    int e = beg;
    for (; e + 15 < end; e += 16) {
        int s0 = colx[e],      s1 = colx[e + 1],  s2 = colx[e + 2],  s3 = colx[e + 3];
        int s4 = colx[e + 4],  s5 = colx[e + 5],  s6 = colx[e + 6],  s7 = colx[e + 7];
        int s8 = colx[e + 8],  s9 = colx[e + 9],  sa = colx[e + 10], sb = colx[e + 11];
        int sc = colx[e + 12], sd = colx[e + 13], se = colx[e + 14], sf = colx[e + 15];
        ushort8_t v0 = hb8[(size_t)s0 * 16 + lane];
        ushort8_t v1 = hb8[(size_t)s1 * 16 + lane];
        ushort8_t v2 = hb8[(size_t)s2 * 16 + lane];
        ushort8_t v3 = hb8[(size_t)s3 * 16 + lane];
        ushort8_t v4 = hb8[(size_t)s4 * 16 + lane];
        ushort8_t v5 = hb8[(size_t)s5 * 16 + lane];
        ushort8_t v6 = hb8[(size_t)s6 * 16 + lane];
        ushort8_t v7 = hb8[(size_t)s7 * 16 + lane];
        ushort8_t v8 = hb8[(size_t)s8 * 16 + lane];
        ushort8_t v9 = hb8[(size_t)s9 * 16 + lane];
        ushort8_t va = hb8[(size_t)sa * 16 + lane];
        ushort8_t vb = hb8[(size_t)sb * 16 + lane];
        ushort8_t vc = hb8[(size_t)sc * 16 + lane];
        ushort8_t vd = hb8[(size_t)sd * 16 + lane];
        ushort8_t ve = hb8[(size_t)se * 16 + lane];
        ushort8_t vf = hb8[(size_t)sf * 16 + lane];
#pragma unroll
        for (int j = 0; j < 8; ++j) {
            a0[j] += bf2f(v0[j]); a1[j] += bf2f(v1[j]);
            a0[j] += bf2f(v2[j]); a1[j] += bf2f(v3[j]);
            a0[j] += bf2f(v4[j]); a1[j] += bf2f(v5[j]);
            a0[j] += bf2f(v6[j]); a1[j] += bf2f(v7[j]);
        }
#pragma unroll
        for (int j = 0; j < 8; ++j) {
            a0[j] += bf2f(v8[j]); a1[j] += bf2f(v9[j]);
            a0[j] += bf2f(va[j]); a1[j] += bf2f(vb[j]);
            a0[j] += bf2f(vc[j]); a1[j] += bf2f(vd[j]);
            a0[j] += bf2f(ve[j]); a1[j] += bf2f(vf[j]);
        }
    }
    for (; e + 7 < end; e += 8) {
        int s0 = colx[e],     s1 = colx[e + 1], s2 = colx[e + 2], s3 = colx[e + 3];
        int s4 = colx[e + 4], s5 = colx[e + 5], s6 = colx[e + 6], s7 = colx[e + 7];
        ushort8_t v0 = hb8[(size_t)s0 * 16 + lane];
        ushort8_t v1 = hb8[(size_t)s1 * 16 + lane];
        ushort8_t v2 = hb8[(size_t)s2 * 16 + lane];
        ushort8_t v3 = hb8[(size_t)s3 * 16 + lane];
        ushort8_t v4 = hb8[(size_t)s4 * 16 + lane];
        ushort8_t v5 = hb8[(size_t)s5 * 16 + lane];
        ushort8_t v6 = hb8[(size_t)s6 * 16 + lane];
        ushort8_t v7 = hb8[(size_t)s7 * 16 + lane];
#pragma unroll
        for (int j = 0; j < 8; ++j) {
            a0[j] += bf2f(v0[j]); a1[j] += bf2f(v1[j]);
            a0[j] += bf2f(v2[j]); a1[j] += bf2f(v3[j]);
            a0[j] += bf2f(v4[j]); a1[j] += bf2f(v5[j]);
            a0[j] += bf2f(v6[j]); a1[j] += bf2f(v7[j]);
        }
    }
    for (; e + 3 < end; e += 4) {
        int s0 = colx[e], s1 = colx[e + 1], s2 = colx[e + 2], s3 = colx[e + 3];
        ushort8_t v0 = hb8[(size_t)s0 * 16 + lane];
        ushort8_t v1 = hb8[(size_t)s1 * 16 + lane];
        ushort8_t v2 = hb8[(size_t)s2 * 16 + lane];
        ushort8_t v3 = hb8[(size_t)s3 * 16 + lane];
#pragma unroll
        for (int j = 0; j < 8; ++j) {
            a0[j] += bf2f(v0[j]); a1[j] += bf2f(v1[j]);
            a0[j] += bf2f(v2[j]); a1[j] += bf2f(v3[j]);
        }
    }
    for (; e < end; ++e) {
        int s = colx[e];
        ushort8_t v = hb8[(size_t)s * 16 + lane];
#pragma unroll
        for (int j = 0; j < 8; ++j) a0[j] += bf2f(v[j]);
    }
    int deg = end - beg;
    float inv = 1.0f / (float)(deg > 1 ? deg : 1);
    ushort8_t o;
#pragma unroll
    for (int j = 0; j < 8; ++j) o[j] = f2bf((a0[j] + a1[j]) * inv);
    // fragment-major store (KF=4): lane's cols lane*8..lane*8+7 = one contiguous j-group
    int T = g >> 4, m = g & 15;
    *(ushort8_t*)&Sf[((size_t)(T * 4 + (lane >> 2)) * 64 + (lane & 3) * 16 + m) * 8] = o;
}

// ---------------- device fn: MFMA GEMM (frag-major A, register-persistent B, prefetch) ----

template <int KF1, int KF2, int DO_ELU>
__device__ __forceinline__ void dev_gemm(
    const u16* __restrict__ A1f, const u16* __restrict__ A2f,
    const u16* __restrict__ B1h, const u16* __restrict__ B1l,
    const u16* __restrict__ B2h, const u16* __restrict__ B2l,
    const float* __restrict__ bias, float* __restrict__ C,
    u16* __restrict__ Hrow, u16* __restrict__ Hf,
    int M, int bid, int gdim)
{
    constexpr int K1 = KF1 * 32;
    constexpr int K2 = KF2 * 32;
    constexpr int KF = KF1 + KF2;
    int lane = threadIdx.x & 63;
    int w    = threadIdx.x >> 6;
    int m16  = lane & 15;
    int quad = lane >> 4;
    int kq   = quad * 8;
    int ng   = (bid >> 3) & 1;
    int mtb  = (bid & 7) | ((bid >> 4) << 3);   // [0, gdim/2)
    int ncol = (ng * 4 + w) * 16 + m16;

    frag_t bh[KF], bl[KF];
    if constexpr (KF1 > 0) {
#pragma unroll
        for (int f = 0; f < KF1; ++f) {
            bh[f] = *(const frag_t*)&B1h[(size_t)ncol * K1 + f * 32 + kq];
            bl[f] = *(const frag_t*)&B1l[(size_t)ncol * K1 + f * 32 + kq];
        }
    }
    if constexpr (KF2 > 0) {
#pragma unroll
        for (int f = 0; f < KF2; ++f) {
            bh[KF1 + f] = *(const frag_t*)&B2h[(size_t)ncol * K2 + f * 32 + kq];
            bl[KF1 + f] = *(const frag_t*)&B2l[(size_t)ncol * K2 + f * 32 + kq];
        }
    }

    float bv = bias[ncol];
    int nMT  = (M + 31) >> 5;
    int step = gdim >> 1;
    int fcol = ncol >> 5;
    int qcol = (ncol & 31) >> 3;
    int jcol = ncol & 7;

    auto loadA = [&](int mt, frag_t (&a0)[KF], frag_t (&a1)[KF]) {
        int T0 = mt * 2, T1 = T0 + 1;   // padded alloc: no guards
        if constexpr (KF1 > 0) {
#pragma unroll
            for (int f = 0; f < KF1; ++f) {
                a0[f] = *(const frag_t*)&A1f[((size_t)(T0 * KF1 + f) * 64 + lane) * 8];
                a1[f] = *(const frag_t*)&A1f[((size_t)(T1 * KF1 + f) * 64 + lane) * 8];
            }
        }
        if constexpr (KF2 > 0) {
#pragma unroll
            for (int f = 0; f < KF2; ++f) {
                a0[KF1 + f] = *(const frag_t*)&A2f[((size_t)(T0 * KF2 + f) * 64 + lane) * 8];
                a1[KF1 + f] = *(const frag_t*)&A2f[((size_t)(T1 * KF2 + f) * 64 + lane) * 8];
            }
        }
    };

    auto compute = [&](int mt, frag_t (&a0)[KF], frag_t (&a1)[KF]) {
        f32x4_t acc0 = (f32x4_t){0.f, 0.f, 0.f, 0.f};
        f32x4_t acc1 = (f32x4_t){0.f, 0.f, 0.f, 0.f};
#pragma unroll
        for (int f = 0; f < KF; ++f) {
            acc0 = __builtin_amdgcn_mfma_f32_16x16x32_bf16(a0[f], bh[f], acc0, 0, 0, 0);
            acc1 = __builtin_amdgcn_mfma_f32_16x16x32_bf16(a1[f], bh[f], acc1, 0, 0, 0);
            acc0 = __builtin_amdgcn_mfma_f32_16x16x32_bf16(a0[f], bl[f], acc0, 0, 0, 0);
            acc1 = __builtin_amdgcn_mfma_f32_16x16x32_bf16(a1[f], bl[f], acc1, 0, 0, 0);
        }
        int rb = mt * 32 + quad * 4;
#pragma unroll
        for (int r = 0; r < 4; ++r) {
#pragma unroll
            for (int half = 0; half < 2; ++half) {
                int row = rb + r + half * 16;
                float av = half ? acc1[r] : acc0[r];
                if (row < M) {
                    float v = av + bv;
                    if constexpr (DO_ELU) v = (v > 0.f) ? v : expm1f(v);
                    if (C) C[(size_t)row * HIDDEN + ncol] = v;
                    if (Hrow) {
                        u16 hv = f2bf(v);
                        Hrow[(size_t)row * HIDDEN + ncol] = hv;
                        Hf[((size_t)((row >> 4) * 4 + fcol) * 64 + qcol * 16 + (row & 15)) * 8 + jcol] = hv;
                    }
                }
            }
        }
    };

    int mt = mtb;
    if (mt < nMT) {
        frag_t xa0[KF], xa1[KF], ya0[KF], ya1[KF];
        loadA(mt, xa0, xa1);
        while (true) {
            int mt2 = mt + step;
            if (mt2 < nMT) loadA(mt2, ya0, ya1);       // prefetch under compute(mt)
            compute(mt, xa0, xa1);
            if (mt2 >= nMT) break;
            int mt3 = mt2 + step;
            if (mt3 < nMT) loadA(mt3, xa0, xa1);       // prefetch under compute(mt2)
            compute(mt2, ya0, ya1);
            if (mt3 >= nMT) break;
            mt = mt3;
        }
    }
}

// layer GEMM wrapper (standalone dispatch)
template <int KF1, int KF2, int DO_ELU>
__global__ __launch_bounds__(256, 2) void k_gemm_mfma(
    const u16* __restrict__ A1f, const u16* __restrict__ A2f,
    const u16* __restrict__ B1h, const u16* __restrict__ B1l,
    const u16* __restrict__ B2h, const u16* __restrict__ B2l,
    const float* __restrict__ bias, float* __restrict__ C,
    u16* __restrict__ Hrow, u16* __restrict__ Hf, int M)
{
    dev_gemm<KF1, KF2, DO_ELU>(A1f, A2f, B1h, B1l, B2h, B2l, bias, C, Hrow, Hf,
                               M, blockIdx.x, gridDim.x);
}

// fused dispatch: LDS-cursor CSR fill (blocks [0,NBF)) || input-projection GEMM (rest).
// Independent: fill writes colx; gemm reads xf/WtI (from hist2_prep), writes hRowA/hfA.

__global__ __launch_bounds__(256, 2) void k_fill2_gemm(
    const int* __restrict__ ei, int E,
    const int* __restrict__ rowp, const u16* __restrict__ base,
    int* __restrict__ colx, int npr, int n, int nbF,
    const u16* __restrict__ xf,
    const u16* __restrict__ WtI_hi, const u16* __restrict__ WtI_lo,
    const float* __restrict__ b_in,
    u16* __restrict__ hRow, u16* __restrict__ hf, int M, int gdim)
{
    __shared__ int cur[MAXNPR];
    if (blockIdx.x < (unsigned)nbF) {
        dev_fill2(ei, E, rowp, base, colx, npr, n, blockIdx.x, cur);
    } else {
        dev_gemm<2, 0, 0>(xf, nullptr, WtI_hi, WtI_lo, nullptr, nullptr,
                          b_in, nullptr, hRow, hf, M, blockIdx.x - nbF, gdim);
    }
}

// ---------------- launch ----------------

extern "C" void kernel_launch(void* const* d_in, const int* in_sizes, int n_in,
                              void* d_out, int out_size, void* d_ws, size_t ws_size,
                              hipStream_t stream) {
    const float* x        = (const float*)d_in[0];
    const int* ei         = (const int*)d_in[1];
    const float* W_in     = (const float*)d_in[2];
    const float* b_in     = (const float*)d_in[3];
    const float* W_self   = (const float*)d_in[4];
    const float* b_self   = (const float*)d_in[5];
    const float* W_nbr    = (const float*)d_in[6];
    float* out = (float*)d_out;

    const int IN_FEAT = 64;
    int N = in_sizes[0] / IN_FEAT;           // 50000
    int E = in_sizes[1] / 2;                 // 800000
    int L = in_sizes[4] / (HIDDEN * HIDDEN); // 3

    char* ws = (char*)d_ws;
    size_t off = 0;
    auto alloc = [&](size_t bytes) -> void* {
        void* p = ws + off;
        off = (off + bytes + 255) & ~(size_t)255;
        return p;
    };

    int nT = ((N + 31) / 32) * 2;            // 16-row tiles, padded to macro-tile pairs

    u16* hRowA = (u16*)alloc((size_t)N * HIDDEN * 2);
    u16* hRowB = (u16*)alloc((size_t)N * HIDDEN * 2);
    u16* hfA   = (u16*)alloc((size_t)nT * 4 * 64 * 8 * 2);   // KF=4 frag-major
    u16* hfB   = (u16*)alloc((size_t)nT * 4 * 64 * 8 * 2);
    u16* xf    = (u16*)alloc((size_t)nT * 2 * 64 * 8 * 2);   // KF=2
    u16* Sf    = (u16*)alloc((size_t)nT * 4 * 64 * 8 * 2);
    u16* WtI_hi = (u16*)alloc(128 * 64 * 2);
    u16* WtI_lo = (u16*)alloc(128 * 64 * 2);
    u16* WtS_hi = (u16*)alloc((size_t)L * 128 * 128 * 2);
    u16* WtS_lo = (u16*)alloc((size_t)L * 128 * 128 * 2);
    u16* WtN_hi = (u16*)alloc((size_t)L * 128 * 128 * 2);
    u16* WtN_lo = (u16*)alloc((size_t)L * 128 * 128 * 2);
    u16* counts = (u16*)alloc((size_t)NC * N * sizeof(u16));
    u16* base   = (u16*)alloc((size_t)NC * N * sizeof(u16));
    int* rowp  = (int*)alloc((size_t)(N + 1) * sizeof(int));
    int* colx  = (int*)alloc((size_t)E * sizeof(int));
    int* bsums = (int*)alloc(1024 * sizeof(int));

    int npr = (N + NR - 1) / NR;   // nodes per XCD range (<= MAXNPR)

    // CSR pass A: LDS histogram (no global atomics, no memset) + prep fused
    k_hist2_prep<<<NR * NC, 256, 0, stream>>>(ei, E, counts, npr, N,
                                              x, W_in, W_self, W_nbr, xf,
                                              WtI_hi, WtI_lo, WtS_hi, WtS_lo,
                                              WtN_hi, WtN_lo, L, N * 8);
    // CSR pass B: deg + chunk prefix + block scan (merged), then cross-block tail
    int nb = (N + 1023) / 1024;
    k_deg_scan<<<nb, 1024, 0, stream>>>(counts, base, rowp, bsums, N);
    k_scan_tail<<<nb, 1024, 0, stream>>>(rowp, bsums, N, nb);

    const int GB = 1024;   // gemm sub-grid: multiple of 16; ~3 tiles/block for prefetch
    const int NBF = NR * NC;  // fill sub-grid (1024)

    // fused: LDS-cursor CSR fill || input projection h = bf16(x @ W_in + b_in)
    k_fill2_gemm<<<NBF + GB, 256, 0, stream>>>(
        ei, E, rowp, base, colx, npr, N, NBF,
        xf, WtI_hi, WtI_lo, b_in, hRowA, hfA, N, GB);

    u16* curRow = hRowA; u16* curF = hfA;
    u16* nxtRow = hRowB; u16* nxtF = hfB;

    for (int l = 0; l < L; ++l) {
        k_agg<<<(N + 15) / 16, 256, 0, stream>>>((const ushort8_t*)curRow, rowp, colx, Sf, N);
        const u16* Wsh = WtS_hi + (size_t)l * 128 * 128;
        const u16* Wsl = WtS_lo + (size_t)l * 128 * 128;
        const u16* Wnh = WtN_hi + (size_t)l * 128 * 128;
        const u16* Wnl = WtN_lo + (size_t)l * 128 * 128;
        const float* bs = b_self + (size_t)l * HIDDEN;
        bool last = (l == L - 1);
        k_gemm_mfma<4, 4, 1><<<GB, 256, 0, stream>>>(
            curF, Sf,
            Wsh, Wsl, Wnh, Wnl,
            bs, last ? out : nullptr,
            last ? nullptr : nxtRow, last ? nullptr : nxtF, N);
        u16* tr = curRow; curRow = nxtRow; nxtRow = tr;
        u16* tf = curF;   curF = nxtF;     nxtF = tf;
    }
}